// Round 3
// baseline (748.334 us; speedup 1.0000x reference)
//
#include <hip/hip_runtime.h>
#include <hip/hip_bf16.h>

#define HDIM 128
static constexpr float BN_S = 0.99999500003749968751f; // 1/sqrt(1+1e-5)

// ---------------- degree count ----------------
__global__ void k_count(const int* __restrict__ edst, int* __restrict__ cnt, int E){
    int e = blockIdx.x * blockDim.x + threadIdx.x;
    if (e < E) atomicAdd(&cnt[edst[e]], 1);
}

// ---------------- exclusive scan (single block) + dis = rsqrt(1+cnt) ----------------
__global__ __launch_bounds__(1024) void k_scan(const int* __restrict__ cnt, int* __restrict__ rowptr,
                                               float* __restrict__ dis, int n){
    __shared__ int part[1024];
    int t = threadIdx.x;
    int CH = (n + 1023) >> 10;
    int base = t * CH;
    int s = 0;
    for (int i = 0; i < CH; ++i){ int idx = base + i; if (idx < n) s += cnt[idx]; }
    part[t] = s;
    __syncthreads();
    for (int off = 1; off < 1024; off <<= 1){
        int v = (t >= off) ? part[t - off] : 0;
        __syncthreads();
        part[t] += v;
        __syncthreads();
    }
    int run = (t == 0) ? 0 : part[t - 1];
    for (int i = 0; i < CH; ++i){
        int idx = base + i;
        if (idx < n){
            rowptr[idx] = run;
            int c = cnt[idx];
            run += c;
            dis[idx] = rsqrtf(1.0f + (float)c);
        }
    }
    if (t == 1023) rowptr[n] = part[1023];
}

// ---------------- CSR fill + per-entry coef ----------------
__global__ void k_fill(const int* __restrict__ esrc, const int* __restrict__ edst,
                       const int* __restrict__ rowptr, int* __restrict__ cursor,
                       const float* __restrict__ dis, int* __restrict__ csrc,
                       float* __restrict__ ccoef, int E){
    int e = blockIdx.x * blockDim.x + threadIdx.x;
    if (e < E){
        int s = esrc[e], d = edst[e];
        int pos = rowptr[d] + atomicAdd(&cursor[d], 1);
        csrc[pos] = s;
        ccoef[pos] = dis[s] * dis[d];
    }
}

__device__ __forceinline__ float f4c(float4 v, int j){
    return (j == 0) ? v.x : (j == 1) ? v.y : (j == 2) ? v.z : v.w;
}

// ---------------- fused inputBN + linear + BN + ReLU : h = relu(bn0(bn_in(x)@W + b)) ----------------
__global__ __launch_bounds__(256) void k_lin(
    const float* __restrict__ x, const float* __restrict__ W,
    const float* __restrict__ bias, const float* __restrict__ ing, const float* __restrict__ inb,
    const float* __restrict__ g0, const float* __restrict__ b0,
    float* __restrict__ hout, int nrows)
{
    __shared__ __align__(16) float sA[64 * 68];   // 64 rows x 64 k (+4 pad)
    __shared__ __align__(16) float sW[64 * 132];  // 64 k x 128 n (+4 pad)
    __shared__ float sing[128], sinb[128];
    int t = threadIdx.x;
    int row0 = blockIdx.x * 64;
    if (t < 128){ sing[t] = ing[t] * BN_S; sinb[t] = inb[t]; }
    int rg = t >> 5, cg = t & 31;
    float acc[8][4];
#pragma unroll
    for (int i = 0; i < 8; ++i)
#pragma unroll
        for (int j = 0; j < 4; ++j) acc[i][j] = 0.f;

    for (int c = 0; c < 2; ++c){
        __syncthreads();
        for (int i = t; i < 1024; i += 256){
            int r = i >> 4, k4 = (i & 15) * 4;
            int gr = row0 + r;
            float4 v = make_float4(0.f, 0.f, 0.f, 0.f);
            if (gr < nrows) v = *(const float4*)&x[(size_t)gr * HDIM + c * 64 + k4];
            int kb = c * 64 + k4;
            v.x = v.x * sing[kb + 0] + sinb[kb + 0];
            v.y = v.y * sing[kb + 1] + sinb[kb + 1];
            v.z = v.z * sing[kb + 2] + sinb[kb + 2];
            v.w = v.w * sing[kb + 3] + sinb[kb + 3];
            *(float4*)&sA[r * 68 + k4] = v;
        }
        for (int i = t; i < 2048; i += 256){
            int kk = i >> 5, n4 = (i & 31) * 4;
            *(float4*)&sW[kk * 132 + n4] = *(const float4*)&W[(size_t)(c * 64 + kk) * HDIM + n4];
        }
        __syncthreads();
        for (int kk = 0; kk < 64; kk += 4){
            float4 a[8];
#pragma unroll
            for (int i = 0; i < 8; ++i) a[i] = *(float4*)&sA[(rg * 8 + i) * 68 + kk];
#pragma unroll
            for (int j = 0; j < 4; ++j){
                float4 w = *(float4*)&sW[(kk + j) * 132 + cg * 4];
#pragma unroll
                for (int i = 0; i < 8; ++i){
                    float av = f4c(a[i], j);
                    acc[i][0] = fmaf(av, w.x, acc[i][0]);
                    acc[i][1] = fmaf(av, w.y, acc[i][1]);
                    acc[i][2] = fmaf(av, w.z, acc[i][2]);
                    acc[i][3] = fmaf(av, w.w, acc[i][3]);
                }
            }
        }
    }
    int col = cg * 4;
    float bs[4], gg[4], bb2[4];
#pragma unroll
    for (int j = 0; j < 4; ++j){ bs[j] = bias[col + j]; gg[j] = g0[col + j]; bb2[j] = b0[col + j]; }
#pragma unroll
    for (int i = 0; i < 8; ++i){
        int gr = row0 + rg * 8 + i;
        if (gr < nrows){
            float4 o;
            o.x = fmaxf(gg[0] * ((acc[i][0] + bs[0]) * BN_S) + bb2[0], 0.f);
            o.y = fmaxf(gg[1] * ((acc[i][1] + bs[1]) * BN_S) + bb2[1], 0.f);
            o.z = fmaxf(gg[2] * ((acc[i][2] + bs[2]) * BN_S) + bb2[2], 0.f);
            o.w = fmaxf(gg[3] * ((acc[i][3] + bs[3]) * BN_S) + bb2[3], 0.f);
            *(float4*)&hout[(size_t)gr * HDIM + col] = o;
        }
    }
}

// ---------------- hw = h @ W (all f32) ----------------
__global__ __launch_bounds__(256) void k_mm(
    const float* __restrict__ A, const float* __restrict__ W,
    float* __restrict__ C, int nrows)
{
    __shared__ __align__(16) float sA[64 * 68];
    __shared__ __align__(16) float sW[64 * 132];
    int t = threadIdx.x;
    int row0 = blockIdx.x * 64;
    int rg = t >> 5, cg = t & 31;
    float acc[8][4];
#pragma unroll
    for (int i = 0; i < 8; ++i)
#pragma unroll
        for (int j = 0; j < 4; ++j) acc[i][j] = 0.f;

    for (int c = 0; c < 2; ++c){
        __syncthreads();
        for (int i = t; i < 1024; i += 256){
            int r = i >> 4, k4 = (i & 15) * 4;
            int gr = row0 + r;
            float4 v = make_float4(0.f, 0.f, 0.f, 0.f);
            if (gr < nrows) v = *(const float4*)&A[(size_t)gr * HDIM + c * 64 + k4];
            *(float4*)&sA[r * 68 + k4] = v;
        }
        for (int i = t; i < 2048; i += 256){
            int kk = i >> 5, n4 = (i & 31) * 4;
            *(float4*)&sW[kk * 132 + n4] = *(const float4*)&W[(size_t)(c * 64 + kk) * HDIM + n4];
        }
        __syncthreads();
        for (int kk = 0; kk < 64; kk += 4){
            float4 a[8];
#pragma unroll
            for (int i = 0; i < 8; ++i) a[i] = *(float4*)&sA[(rg * 8 + i) * 68 + kk];
#pragma unroll
            for (int j = 0; j < 4; ++j){
                float4 w = *(float4*)&sW[(kk + j) * 132 + cg * 4];
#pragma unroll
                for (int i = 0; i < 8; ++i){
                    float av = f4c(a[i], j);
                    acc[i][0] = fmaf(av, w.x, acc[i][0]);
                    acc[i][1] = fmaf(av, w.y, acc[i][1]);
                    acc[i][2] = fmaf(av, w.z, acc[i][2]);
                    acc[i][3] = fmaf(av, w.w, acc[i][3]);
                }
            }
        }
    }
    int col = cg * 4;
#pragma unroll
    for (int i = 0; i < 8; ++i){
        int gr = row0 + rg * 8 + i;
        if (gr < nrows)
            *(float4*)&C[(size_t)gr * HDIM + col] =
                make_float4(acc[i][0], acc[i][1], acc[i][2], acc[i][3]);
    }
}

// ---------------- CSR aggregate + self loop + bias + BN + ReLU + residual ----------------
__global__ __launch_bounds__(128) void k_agg(
    const float* __restrict__ hw, float* __restrict__ h,
    const int* __restrict__ rowptr, const int* __restrict__ csrc,
    const float* __restrict__ ccoef, const float* __restrict__ dis,
    const float* __restrict__ cb, const float* __restrict__ bg, const float* __restrict__ bb)
{
    int row = blockIdx.x;
    int j = threadIdx.x;
    __shared__ int ss[128];
    __shared__ float sc[128];
    int b = rowptr[row], e = rowptr[row + 1];
    float acc = 0.f;
    for (int chunk = b; chunk < e; chunk += 128){
        int nn = min(128, e - chunk);
        __syncthreads();
        if (j < nn){ ss[j] = csrc[chunk + j]; sc[j] = ccoef[chunk + j]; }
        __syncthreads();
        for (int p = 0; p < nn; ++p)
            acc = fmaf(hw[(size_t)ss[p] * HDIM + j], sc[p], acc);
    }
    float d = dis[row];
    float v = (acc + hw[(size_t)row * HDIM + j] * (d * d) + cb[j]) * BN_S;
    v = bg[j] * v + bb[j];
    h[(size_t)row * HDIM + j] += fmaxf(v, 0.f);
}

// ---------------- fused per-head 3-layer MLPs; blockIdx.y: 0..3 regression, 4 outcome ----------------
__global__ __launch_bounds__(256) void k_heads(
    const float* __restrict__ h, const int* __restrict__ gidx,
    const float* __restrict__ hW1, const float* __restrict__ hb1,
    const float* __restrict__ hg1, const float* __restrict__ hbb1,
    const float* __restrict__ hW2, const float* __restrict__ hb2,
    const float* __restrict__ hW3, const float* __restrict__ hb3,
    const float* __restrict__ oW1, const float* __restrict__ ob1,
    const float* __restrict__ og1, const float* __restrict__ obb1,
    const float* __restrict__ oW2, const float* __restrict__ ob2,
    const float* __restrict__ og2, const float* __restrict__ obb2,
    const float* __restrict__ oW3, const float* __restrict__ ob3,
    float* __restrict__ out, int G)
{
    int t = threadIdx.x;
    int g0 = blockIdx.x * 32;
    int y = blockIdx.y;
    __shared__ __align__(16) float sx[32 * 132];
    __shared__ float sz1[32 * 65];
    __shared__ float sz2[32 * 33];
    __shared__ int sgi[32];

    bool bn2 = (y == 4);
    const float* W1  = bn2 ? oW1  : (hW1 + y * (128 * 64));
    const float* b1  = bn2 ? ob1  : (hb1 + y * 64);
    const float* g1  = bn2 ? og1  : (hg1 + y * 64);
    const float* bb1 = bn2 ? obb1 : (hbb1 + y * 64);
    const float* W2  = bn2 ? oW2  : (hW2 + y * (64 * 32));
    const float* b2  = bn2 ? ob2  : (hb2 + y * 32);
    const float* W3  = bn2 ? oW3  : (hW3 + y * 32);
    const float* b3  = bn2 ? ob3  : (hb3 + y);

    if (t < 32){ int g = g0 + t; sgi[t] = (g < G) ? gidx[g] : 0; }
    __syncthreads();
    for (int i = t; i < 1024; i += 256){
        int r = i >> 5, k4 = (i & 31) * 4;
        *(float4*)&sx[r * 132 + k4] = *(const float4*)&h[(size_t)sgi[r] * HDIM + k4];
    }
    __syncthreads();

    // layer 1: [32,128] @ [128,64] + BN + relu
    {
        int g = t >> 3;
        int oc = (t & 7) * 8;
        float acc[8];
#pragma unroll
        for (int j = 0; j < 8; ++j) acc[j] = 0.f;
        for (int kk = 0; kk < 128; kk += 4){
            float4 a = *(float4*)&sx[g * 132 + kk];
#pragma unroll
            for (int j = 0; j < 4; ++j){
                float av = f4c(a, j);
                float4 w0 = __ldg((const float4*)&W1[(kk + j) * 64 + oc]);
                float4 w1 = __ldg((const float4*)&W1[(kk + j) * 64 + oc + 4]);
                acc[0] = fmaf(av, w0.x, acc[0]);
                acc[1] = fmaf(av, w0.y, acc[1]);
                acc[2] = fmaf(av, w0.z, acc[2]);
                acc[3] = fmaf(av, w0.w, acc[3]);
                acc[4] = fmaf(av, w1.x, acc[4]);
                acc[5] = fmaf(av, w1.y, acc[5]);
                acc[6] = fmaf(av, w1.z, acc[6]);
                acc[7] = fmaf(av, w1.w, acc[7]);
            }
        }
#pragma unroll
        for (int j = 0; j < 8; ++j){
            int o = oc + j;
            float v = __ldg(&g1[o]) * ((acc[j] + __ldg(&b1[o])) * BN_S) + __ldg(&bb1[o]);
            sz1[g * 65 + o] = fmaxf(v, 0.f);
        }
    }
    __syncthreads();
    // layer 2: [32,64] @ [64,32] (+BN for outcome) + relu
    {
        int g = t >> 3;
        int pc = (t & 7) * 4;
        float acc[4] = {0.f, 0.f, 0.f, 0.f};
        for (int o = 0; o < 64; ++o){
            float a = sz1[g * 65 + o];
            float4 w = __ldg((const float4*)&W2[o * 32 + pc]);
            acc[0] = fmaf(a, w.x, acc[0]);
            acc[1] = fmaf(a, w.y, acc[1]);
            acc[2] = fmaf(a, w.z, acc[2]);
            acc[3] = fmaf(a, w.w, acc[3]);
        }
#pragma unroll
        for (int j = 0; j < 4; ++j){
            int p = pc + j;
            float v = acc[j] + __ldg(&b2[p]);
            if (bn2) v = __ldg(&og2[p]) * (v * BN_S) + __ldg(&obb2[p]);
            sz2[g * 33 + p] = fmaxf(v, 0.f);
        }
    }
    __syncthreads();
    // layer 3
    if (!bn2){
        if (t < 32 && g0 + t < G){
            float s = 0.f;
            for (int p = 0; p < 32; ++p) s = fmaf(sz2[t * 33 + p], __ldg(&W3[p]), s);
            out[(size_t)(g0 + t) * 7 + y] = s + __ldg(&b3[0]);
        }
    } else {
        if (t < 96){
            int g = t / 3, c = t % 3;
            if (g0 + g < G){
                float s = 0.f;
                for (int p = 0; p < 32; ++p) s = fmaf(sz2[g * 33 + p], __ldg(&W3[p * 3 + c]), s);
                out[(size_t)(g0 + g) * 7 + 4 + c] = s + __ldg(&b3[c]);
            }
        }
    }
}

extern "C" void kernel_launch(void* const* d_in, const int* in_sizes, int n_in,
                              void* d_out, int out_size, void* d_ws, size_t ws_size,
                              hipStream_t stream)
{
    const float* x    = (const float*)d_in[0];
    const int* esrc   = (const int*)d_in[1];
    const int* edst   = (const int*)d_in[2];
    const int* gidx   = (const int*)d_in[3];
    const float* in_g = (const float*)d_in[4];
    const float* in_b = (const float*)d_in[5];
    const float* lin_W = (const float*)d_in[6];
    const float* lin_b = (const float*)d_in[7];
    const float* bn0_g = (const float*)d_in[8];
    const float* bn0_b = (const float*)d_in[9];
    const float* cW[3] = {(const float*)d_in[10], (const float*)d_in[14], (const float*)d_in[18]};
    const float* cb[3] = {(const float*)d_in[11], (const float*)d_in[15], (const float*)d_in[19]};
    const float* bg[3] = {(const float*)d_in[12], (const float*)d_in[16], (const float*)d_in[20]};
    const float* bb[3] = {(const float*)d_in[13], (const float*)d_in[17], (const float*)d_in[21]};
    const float* hW1 = (const float*)d_in[22];
    const float* hb1 = (const float*)d_in[23];
    const float* hg1 = (const float*)d_in[24];
    const float* hbb1 = (const float*)d_in[25];
    const float* hW2 = (const float*)d_in[26];
    const float* hb2 = (const float*)d_in[27];
    const float* hW3 = (const float*)d_in[28];
    const float* hb3 = (const float*)d_in[29];
    const float* oW1 = (const float*)d_in[30];
    const float* ob1 = (const float*)d_in[31];
    const float* og1 = (const float*)d_in[32];
    const float* obb1 = (const float*)d_in[33];
    const float* oW2 = (const float*)d_in[34];
    const float* ob2 = (const float*)d_in[35];
    const float* og2 = (const float*)d_in[36];
    const float* obb2 = (const float*)d_in[37];
    const float* oW3 = (const float*)d_in[38];
    const float* ob3 = (const float*)d_in[39];

    const int N = in_sizes[0] / HDIM;
    const int E = in_sizes[1];
    const int G = in_sizes[3];

    char* wsp = (char*)d_ws;
    size_t off = 0;
    auto alloc = [&](size_t bytes) -> char* {
        char* p = wsp + off;
        off = (off + bytes + 255) & ~(size_t)255;
        return p;
    };
    float* dis    = (float*)alloc((size_t)N * 4);
    int* rowptr   = (int*)alloc((size_t)(N + 1) * 4);
    int* cnt      = (int*)alloc((size_t)N * 4);
    int* cursor   = (int*)alloc((size_t)N * 4);
    int* csrc     = (int*)alloc((size_t)E * 4);
    float* ccoef  = (float*)alloc((size_t)E * 4);
    float* hbuf   = (float*)alloc((size_t)N * HDIM * 4);
    float* hwbuf  = (float*)alloc((size_t)N * HDIM * 4);

    hipMemsetAsync(cnt, 0, (size_t)N * 4, stream);
    hipMemsetAsync(cursor, 0, (size_t)N * 4, stream);

    k_count<<<dim3((E + 255) / 256), dim3(256), 0, stream>>>(edst, cnt, E);
    k_scan<<<dim3(1), dim3(1024), 0, stream>>>(cnt, rowptr, dis, N);
    k_fill<<<dim3((E + 255) / 256), dim3(256), 0, stream>>>(esrc, edst, rowptr, cursor, dis, csrc, ccoef, E);

    int gb = (N + 63) / 64;
    k_lin<<<dim3(gb), dim3(256), 0, stream>>>(x, lin_W, lin_b, in_g, in_b, bn0_g, bn0_b, hbuf, N);
    for (int l = 0; l < 3; ++l){
        k_mm<<<dim3(gb), dim3(256), 0, stream>>>(hbuf, cW[l], hwbuf, N);
        k_agg<<<dim3(N), dim3(128), 0, stream>>>(hwbuf, hbuf, rowptr, csrc, ccoef, dis,
                                                 cb[l], bg[l], bb[l]);
    }
    k_heads<<<dim3((G + 31) / 32, 5), dim3(256), 0, stream>>>(
        hbuf, gidx,
        hW1, hb1, hg1, hbb1, hW2, hb2, hW3, hb3,
        oW1, ob1, og1, obb1, oW2, ob2, og2, obb2,
        oW3, ob3, (float*)d_out, G);
}

// Round 4
// 739.328 us; speedup vs baseline: 1.0122x; 1.0122x over previous
//
#include <hip/hip_runtime.h>
#include <hip/hip_bf16.h>

#define HDIM 128
static constexpr float BN_S = 0.99999500003749968751f; // 1/sqrt(1+1e-5)

// ---------------- degree count ----------------
__global__ void k_count(const int* __restrict__ edst, int* __restrict__ cnt, int E){
    int e = blockIdx.x * blockDim.x + threadIdx.x;
    if (e < E) atomicAdd(&cnt[edst[e]], 1);
}

// ---------------- exclusive scan (single block) + dis = rsqrt(1+cnt) ----------------
__global__ __launch_bounds__(1024) void k_scan(const int* __restrict__ cnt, int* __restrict__ rowptr,
                                               float* __restrict__ dis, int n){
    __shared__ int part[1024];
    int t = threadIdx.x;
    int CH = (n + 1023) >> 10;
    int base = t * CH;
    int s = 0;
    for (int i = 0; i < CH; ++i){ int idx = base + i; if (idx < n) s += cnt[idx]; }
    part[t] = s;
    __syncthreads();
    for (int off = 1; off < 1024; off <<= 1){
        int v = (t >= off) ? part[t - off] : 0;
        __syncthreads();
        part[t] += v;
        __syncthreads();
    }
    int run = (t == 0) ? 0 : part[t - 1];
    for (int i = 0; i < CH; ++i){
        int idx = base + i;
        if (idx < n){
            rowptr[idx] = run;
            int c = cnt[idx];
            run += c;
            dis[idx] = rsqrtf(1.0f + (float)c);
        }
    }
    if (t == 1023) rowptr[n] = part[1023];
}

// ---------------- CSR fill + per-entry coef ----------------
__global__ void k_fill(const int* __restrict__ esrc, const int* __restrict__ edst,
                       const int* __restrict__ rowptr, int* __restrict__ cursor,
                       const float* __restrict__ dis, int* __restrict__ csrc,
                       float* __restrict__ ccoef, int E){
    int e = blockIdx.x * blockDim.x + threadIdx.x;
    if (e < E){
        int s = esrc[e], d = edst[e];
        int pos = rowptr[d] + atomicAdd(&cursor[d], 1);
        csrc[pos] = s;
        ccoef[pos] = dis[s] * dis[d];
    }
}

__device__ __forceinline__ float f4c(float4 v, int j){
    return (j == 0) ? v.x : (j == 1) ? v.y : (j == 2) ? v.z : v.w;
}

// ---------------- fused inputBN + linear + BN + ReLU : h = relu(bn0(bn_in(x)@W + b)) ----------------
__global__ __launch_bounds__(256) void k_lin(
    const float* __restrict__ x, const float* __restrict__ W,
    const float* __restrict__ bias, const float* __restrict__ ing, const float* __restrict__ inb,
    const float* __restrict__ g0, const float* __restrict__ b0,
    float* __restrict__ hout, int nrows)
{
    __shared__ __align__(16) float sA[64 * 68];   // 64 rows x 64 k (+4 pad)
    __shared__ __align__(16) float sW[64 * 132];  // 64 k x 128 n (+4 pad)
    __shared__ float sing[128], sinb[128];
    int t = threadIdx.x;
    int row0 = blockIdx.x * 64;
    if (t < 128){ sing[t] = ing[t] * BN_S; sinb[t] = inb[t]; }
    int rg = t >> 5, cg = t & 31;
    float acc[8][4];
#pragma unroll
    for (int i = 0; i < 8; ++i)
#pragma unroll
        for (int j = 0; j < 4; ++j) acc[i][j] = 0.f;

    for (int c = 0; c < 2; ++c){
        __syncthreads();
        for (int i = t; i < 1024; i += 256){
            int r = i >> 4, k4 = (i & 15) * 4;
            int gr = row0 + r;
            float4 v = make_float4(0.f, 0.f, 0.f, 0.f);
            if (gr < nrows) v = *(const float4*)&x[(size_t)gr * HDIM + c * 64 + k4];
            int kb = c * 64 + k4;
            v.x = v.x * sing[kb + 0] + sinb[kb + 0];
            v.y = v.y * sing[kb + 1] + sinb[kb + 1];
            v.z = v.z * sing[kb + 2] + sinb[kb + 2];
            v.w = v.w * sing[kb + 3] + sinb[kb + 3];
            *(float4*)&sA[r * 68 + k4] = v;
        }
        for (int i = t; i < 2048; i += 256){
            int kk = i >> 5, n4 = (i & 31) * 4;
            *(float4*)&sW[kk * 132 + n4] = *(const float4*)&W[(size_t)(c * 64 + kk) * HDIM + n4];
        }
        __syncthreads();
        for (int kk = 0; kk < 64; kk += 4){
            float4 a[8];
#pragma unroll
            for (int i = 0; i < 8; ++i) a[i] = *(float4*)&sA[(rg * 8 + i) * 68 + kk];
#pragma unroll
            for (int j = 0; j < 4; ++j){
                float4 w = *(float4*)&sW[(kk + j) * 132 + cg * 4];
#pragma unroll
                for (int i = 0; i < 8; ++i){
                    float av = f4c(a[i], j);
                    acc[i][0] = fmaf(av, w.x, acc[i][0]);
                    acc[i][1] = fmaf(av, w.y, acc[i][1]);
                    acc[i][2] = fmaf(av, w.z, acc[i][2]);
                    acc[i][3] = fmaf(av, w.w, acc[i][3]);
                }
            }
        }
    }
    int col = cg * 4;
    float bs[4], gg[4], bb2[4];
#pragma unroll
    for (int j = 0; j < 4; ++j){ bs[j] = bias[col + j]; gg[j] = g0[col + j]; bb2[j] = b0[col + j]; }
#pragma unroll
    for (int i = 0; i < 8; ++i){
        int gr = row0 + rg * 8 + i;
        if (gr < nrows){
            float4 o;
            o.x = fmaxf(gg[0] * ((acc[i][0] + bs[0]) * BN_S) + bb2[0], 0.f);
            o.y = fmaxf(gg[1] * ((acc[i][1] + bs[1]) * BN_S) + bb2[1], 0.f);
            o.z = fmaxf(gg[2] * ((acc[i][2] + bs[2]) * BN_S) + bb2[2], 0.f);
            o.w = fmaxf(gg[3] * ((acc[i][3] + bs[3]) * BN_S) + bb2[3], 0.f);
            *(float4*)&hout[(size_t)gr * HDIM + col] = o;
        }
    }
}

// ---------------- hw = h @ W (all f32) ----------------
__global__ __launch_bounds__(256) void k_mm(
    const float* __restrict__ A, const float* __restrict__ W,
    float* __restrict__ C, int nrows)
{
    __shared__ __align__(16) float sA[64 * 68];
    __shared__ __align__(16) float sW[64 * 132];
    int t = threadIdx.x;
    int row0 = blockIdx.x * 64;
    int rg = t >> 5, cg = t & 31;
    float acc[8][4];
#pragma unroll
    for (int i = 0; i < 8; ++i)
#pragma unroll
        for (int j = 0; j < 4; ++j) acc[i][j] = 0.f;

    for (int c = 0; c < 2; ++c){
        __syncthreads();
        for (int i = t; i < 1024; i += 256){
            int r = i >> 4, k4 = (i & 15) * 4;
            int gr = row0 + r;
            float4 v = make_float4(0.f, 0.f, 0.f, 0.f);
            if (gr < nrows) v = *(const float4*)&A[(size_t)gr * HDIM + c * 64 + k4];
            *(float4*)&sA[r * 68 + k4] = v;
        }
        for (int i = t; i < 2048; i += 256){
            int kk = i >> 5, n4 = (i & 31) * 4;
            *(float4*)&sW[kk * 132 + n4] = *(const float4*)&W[(size_t)(c * 64 + kk) * HDIM + n4];
        }
        __syncthreads();
        for (int kk = 0; kk < 64; kk += 4){
            float4 a[8];
#pragma unroll
            for (int i = 0; i < 8; ++i) a[i] = *(float4*)&sA[(rg * 8 + i) * 68 + kk];
#pragma unroll
            for (int j = 0; j < 4; ++j){
                float4 w = *(float4*)&sW[(kk + j) * 132 + cg * 4];
#pragma unroll
                for (int i = 0; i < 8; ++i){
                    float av = f4c(a[i], j);
                    acc[i][0] = fmaf(av, w.x, acc[i][0]);
                    acc[i][1] = fmaf(av, w.y, acc[i][1]);
                    acc[i][2] = fmaf(av, w.z, acc[i][2]);
                    acc[i][3] = fmaf(av, w.w, acc[i][3]);
                }
            }
        }
    }
    int col = cg * 4;
#pragma unroll
    for (int i = 0; i < 8; ++i){
        int gr = row0 + rg * 8 + i;
        if (gr < nrows)
            *(float4*)&C[(size_t)gr * HDIM + col] =
                make_float4(acc[i][0], acc[i][1], acc[i][2], acc[i][3]);
    }
}

// ---------------- CSR aggregate, wave-per-row: no LDS, no barriers ----------------
__global__ __launch_bounds__(256) void k_agg(
    const float* __restrict__ hw, float* __restrict__ h,
    const int* __restrict__ rowptr, const int* __restrict__ csrc,
    const float* __restrict__ ccoef, const float* __restrict__ dis,
    const float* __restrict__ cb, const float* __restrict__ bg, const float* __restrict__ bb,
    int N)
{
    int row = blockIdx.x * 4 + (threadIdx.x >> 6);
    if (row >= N) return;
    int lane = threadIdx.x & 63;
    const float2* hw2 = (const float2*)hw;
    int b = rowptr[row], e = rowptr[row + 1];
    float ax = 0.f, ay = 0.f;
    int p = b;
    for (; p + 4 <= e; p += 4){
        int s0 = csrc[p], s1 = csrc[p + 1], s2 = csrc[p + 2], s3 = csrc[p + 3];
        float c0 = ccoef[p], c1 = ccoef[p + 1], c2 = ccoef[p + 2], c3 = ccoef[p + 3];
        float2 v0 = hw2[(size_t)s0 * 64 + lane];
        float2 v1 = hw2[(size_t)s1 * 64 + lane];
        float2 v2 = hw2[(size_t)s2 * 64 + lane];
        float2 v3 = hw2[(size_t)s3 * 64 + lane];
        ax = fmaf(v0.x, c0, ax); ay = fmaf(v0.y, c0, ay);
        ax = fmaf(v1.x, c1, ax); ay = fmaf(v1.y, c1, ay);
        ax = fmaf(v2.x, c2, ax); ay = fmaf(v2.y, c2, ay);
        ax = fmaf(v3.x, c3, ax); ay = fmaf(v3.y, c3, ay);
    }
    for (; p < e; ++p){
        int s = csrc[p];
        float c = ccoef[p];
        float2 v = hw2[(size_t)s * 64 + lane];
        ax = fmaf(v.x, c, ax); ay = fmaf(v.y, c, ay);
    }
    float d = dis[row];
    float dd = d * d;
    float2 self = hw2[(size_t)row * 64 + lane];
    float2 cbv = ((const float2*)cb)[lane];
    float2 gv  = ((const float2*)bg)[lane];
    float2 bv  = ((const float2*)bb)[lane];
    float vx = gv.x * ((ax + self.x * dd + cbv.x) * BN_S) + bv.x;
    float vy = gv.y * ((ay + self.y * dd + cbv.y) * BN_S) + bv.y;
    float2* h2 = (float2*)h;
    float2 cur = h2[(size_t)row * 64 + lane];
    cur.x += fmaxf(vx, 0.f);
    cur.y += fmaxf(vy, 0.f);
    h2[(size_t)row * 64 + lane] = cur;
}

// ---------------- fused per-head 3-layer MLPs, LDS-staged weights ----------------
__global__ __launch_bounds__(256) void k_heads(
    const float* __restrict__ h, const int* __restrict__ gidx,
    const float* __restrict__ hW1, const float* __restrict__ hb1,
    const float* __restrict__ hg1, const float* __restrict__ hbb1,
    const float* __restrict__ hW2, const float* __restrict__ hb2,
    const float* __restrict__ hW3, const float* __restrict__ hb3,
    const float* __restrict__ oW1, const float* __restrict__ ob1,
    const float* __restrict__ og1, const float* __restrict__ obb1,
    const float* __restrict__ oW2, const float* __restrict__ ob2,
    const float* __restrict__ og2, const float* __restrict__ obb2,
    const float* __restrict__ oW3, const float* __restrict__ ob3,
    float* __restrict__ out, int G)
{
    int t = threadIdx.x;
    int g0 = blockIdx.x * 32;
    int y = blockIdx.y;
    __shared__ __align__(16) float4 sW1[2048];   // 128x64 f32 = 32KB
    __shared__ __align__(16) float4 sW2[512];    // 64x32 f32 = 8KB
    __shared__ __align__(16) float sx[32 * 132];
    __shared__ float sz1[32 * 65];
    __shared__ float sz2[32 * 33];
    __shared__ float sb1[64], sg1[64], sbb1[64];
    __shared__ float sb2[32], sg2[32], sbb2[32];
    __shared__ float sW3[96];
    __shared__ float sb3[3];
    __shared__ int sgi[32];

    bool bn2 = (y == 4);
    const float4* W1 = (const float4*)(bn2 ? oW1 : hW1 + y * (128 * 64));
    const float* b1  = bn2 ? ob1  : (hb1 + y * 64);
    const float* g1  = bn2 ? og1  : (hg1 + y * 64);
    const float* bb1 = bn2 ? obb1 : (hbb1 + y * 64);
    const float4* W2 = (const float4*)(bn2 ? oW2 : hW2 + y * (64 * 32));
    const float* b2  = bn2 ? ob2  : (hb2 + y * 32);
    const float* W3  = bn2 ? oW3  : (hW3 + y * 32);
    const float* b3  = bn2 ? ob3  : (hb3 + y);
    int nc3 = bn2 ? 3 : 1;

    if (t < 32){ int g = g0 + t; sgi[t] = (g < G) ? gidx[g] : 0; }
    __syncthreads();
    for (int i = t; i < 2048; i += 256) sW1[i] = W1[i];
    for (int i = t; i < 512; i += 256) sW2[i] = W2[i];
    for (int i = t; i < 1024; i += 256){
        int r = i >> 5, k4 = (i & 31) * 4;
        *(float4*)&sx[r * 132 + k4] = *(const float4*)&h[(size_t)sgi[r] * HDIM + k4];
    }
    if (t < 64){ sb1[t] = b1[t]; sg1[t] = g1[t]; sbb1[t] = bb1[t]; }
    else if (t < 96){
        int p = t - 64;
        sb2[p] = b2[p];
        sg2[p] = bn2 ? og2[p] : 1.f;
        sbb2[p] = bn2 ? obb2[p] : 0.f;
    }
    else if (t < 192){
        int i = t - 96;
        sW3[i] = (i < 32 * nc3) ? W3[i] : 0.f;
    }
    else if (t < 195){
        int i = t - 192;
        sb3[i] = (i < nc3) ? b3[i] : 0.f;
    }
    __syncthreads();

    // layer 1: [32,128] @ [128,64] + BN + relu
    {
        int g = t >> 3;
        int oc = (t & 7) * 8;
        float acc[8];
#pragma unroll
        for (int j = 0; j < 8; ++j) acc[j] = 0.f;
        for (int kk = 0; kk < 128; kk += 4){
            float4 a = *(float4*)&sx[g * 132 + kk];
#pragma unroll
            for (int j = 0; j < 4; ++j){
                float av = f4c(a, j);
                float4 w0 = sW1[(kk + j) * 16 + (oc >> 2)];
                float4 w1 = sW1[(kk + j) * 16 + (oc >> 2) + 1];
                acc[0] = fmaf(av, w0.x, acc[0]);
                acc[1] = fmaf(av, w0.y, acc[1]);
                acc[2] = fmaf(av, w0.z, acc[2]);
                acc[3] = fmaf(av, w0.w, acc[3]);
                acc[4] = fmaf(av, w1.x, acc[4]);
                acc[5] = fmaf(av, w1.y, acc[5]);
                acc[6] = fmaf(av, w1.z, acc[6]);
                acc[7] = fmaf(av, w1.w, acc[7]);
            }
        }
#pragma unroll
        for (int j = 0; j < 8; ++j){
            int o = oc + j;
            float v = sg1[o] * ((acc[j] + sb1[o]) * BN_S) + sbb1[o];
            sz1[g * 65 + o] = fmaxf(v, 0.f);
        }
    }
    __syncthreads();
    // layer 2: [32,64] @ [64,32] (+BN for outcome) + relu
    {
        int g = t >> 3;
        int pc = (t & 7) * 4;
        float acc[4] = {0.f, 0.f, 0.f, 0.f};
        for (int o = 0; o < 64; ++o){
            float a = sz1[g * 65 + o];
            float4 w = sW2[o * 8 + (pc >> 2)];
            acc[0] = fmaf(a, w.x, acc[0]);
            acc[1] = fmaf(a, w.y, acc[1]);
            acc[2] = fmaf(a, w.z, acc[2]);
            acc[3] = fmaf(a, w.w, acc[3]);
        }
#pragma unroll
        for (int j = 0; j < 4; ++j){
            int p = pc + j;
            float v = acc[j] + sb2[p];
            if (bn2) v = sg2[p] * (v * BN_S) + sbb2[p];
            sz2[g * 33 + p] = fmaxf(v, 0.f);
        }
    }
    __syncthreads();
    // layer 3
    if (!bn2){
        if (t < 32 && g0 + t < G){
            float s = 0.f;
#pragma unroll
            for (int p = 0; p < 32; ++p) s = fmaf(sz2[t * 33 + p], sW3[p], s);
            out[(size_t)(g0 + t) * 7 + y] = s + sb3[0];
        }
    } else {
        if (t < 96){
            int g = t / 3, c = t % 3;
            if (g0 + g < G){
                float s = 0.f;
#pragma unroll
                for (int p = 0; p < 32; ++p) s = fmaf(sz2[g * 33 + p], sW3[p * 3 + c], s);
                out[(size_t)(g0 + g) * 7 + 4 + c] = s + sb3[c];
            }
        }
    }
}

extern "C" void kernel_launch(void* const* d_in, const int* in_sizes, int n_in,
                              void* d_out, int out_size, void* d_ws, size_t ws_size,
                              hipStream_t stream)
{
    const float* x    = (const float*)d_in[0];
    const int* esrc   = (const int*)d_in[1];
    const int* edst   = (const int*)d_in[2];
    const int* gidx   = (const int*)d_in[3];
    const float* in_g = (const float*)d_in[4];
    const float* in_b = (const float*)d_in[5];
    const float* lin_W = (const float*)d_in[6];
    const float* lin_b = (const float*)d_in[7];
    const float* bn0_g = (const float*)d_in[8];
    const float* bn0_b = (const float*)d_in[9];
    const float* cW[3] = {(const float*)d_in[10], (const float*)d_in[14], (const float*)d_in[18]};
    const float* cb[3] = {(const float*)d_in[11], (const float*)d_in[15], (const float*)d_in[19]};
    const float* bg[3] = {(const float*)d_in[12], (const float*)d_in[16], (const float*)d_in[20]};
    const float* bb[3] = {(const float*)d_in[13], (const float*)d_in[17], (const float*)d_in[21]};
    const float* hW1 = (const float*)d_in[22];
    const float* hb1 = (const float*)d_in[23];
    const float* hg1 = (const float*)d_in[24];
    const float* hbb1 = (const float*)d_in[25];
    const float* hW2 = (const float*)d_in[26];
    const float* hb2 = (const float*)d_in[27];
    const float* hW3 = (const float*)d_in[28];
    const float* hb3 = (const float*)d_in[29];
    const float* oW1 = (const float*)d_in[30];
    const float* ob1 = (const float*)d_in[31];
    const float* og1 = (const float*)d_in[32];
    const float* obb1 = (const float*)d_in[33];
    const float* oW2 = (const float*)d_in[34];
    const float* ob2 = (const float*)d_in[35];
    const float* og2 = (const float*)d_in[36];
    const float* obb2 = (const float*)d_in[37];
    const float* oW3 = (const float*)d_in[38];
    const float* ob3 = (const float*)d_in[39];

    const int N = in_sizes[0] / HDIM;
    const int E = in_sizes[1];
    const int G = in_sizes[3];

    char* wsp = (char*)d_ws;
    size_t off = 0;
    auto alloc = [&](size_t bytes) -> char* {
        char* p = wsp + off;
        off = (off + bytes + 255) & ~(size_t)255;
        return p;
    };
    float* dis    = (float*)alloc((size_t)N * 4);
    int* rowptr   = (int*)alloc((size_t)(N + 1) * 4);
    int* cnt      = (int*)alloc((size_t)N * 4);
    int* cursor   = (int*)alloc((size_t)N * 4);
    int* csrc     = (int*)alloc((size_t)E * 4);
    float* ccoef  = (float*)alloc((size_t)E * 4);
    float* hbuf   = (float*)alloc((size_t)N * HDIM * 4);
    float* hwbuf  = (float*)alloc((size_t)N * HDIM * 4);

    hipMemsetAsync(cnt, 0, (size_t)N * 4, stream);
    hipMemsetAsync(cursor, 0, (size_t)N * 4, stream);

    k_count<<<dim3((E + 255) / 256), dim3(256), 0, stream>>>(edst, cnt, E);
    k_scan<<<dim3(1), dim3(1024), 0, stream>>>(cnt, rowptr, dis, N);
    k_fill<<<dim3((E + 255) / 256), dim3(256), 0, stream>>>(esrc, edst, rowptr, cursor, dis, csrc, ccoef, E);

    int gb = (N + 63) / 64;
    k_lin<<<dim3(gb), dim3(256), 0, stream>>>(x, lin_W, lin_b, in_g, in_b, bn0_g, bn0_b, hbuf, N);
    for (int l = 0; l < 3; ++l){
        k_mm<<<dim3(gb), dim3(256), 0, stream>>>(hbuf, cW[l], hwbuf, N);
        k_agg<<<dim3((N + 3) / 4), dim3(256), 0, stream>>>(hwbuf, hbuf, rowptr, csrc, ccoef, dis,
                                                           cb[l], bg[l], bb[l], N);
    }
    k_heads<<<dim3((G + 31) / 32, 5), dim3(256), 0, stream>>>(
        hbuf, gidx,
        hW1, hb1, hg1, hbb1, hW2, hb2, hW3, hb3,
        oW1, ob1, og1, obb1, oW2, ob2, og2, obb2,
        oW3, ob3, (float*)d_out, G);
}

// Round 5
// 478.673 us; speedup vs baseline: 1.5634x; 1.5445x over previous
//
#include <hip/hip_runtime.h>
#include <hip/hip_bf16.h>

#define HDIM 128
static constexpr float BN_S = 0.99999500003749968751f; // 1/sqrt(1+1e-5)

typedef float f32x4 __attribute__((ext_vector_type(4)));
typedef short s16x8 __attribute__((ext_vector_type(8)));

union U128 { uint4 u; s16x8 s; };

__device__ __forceinline__ unsigned short f2bs(float f){
    union{float f; unsigned u;} c; c.f = f;
    unsigned r = c.u + 0x7fffu + ((c.u >> 16) & 1u);
    return (unsigned short)(r >> 16);
}
__device__ __forceinline__ float bs2f(unsigned short s){
    union{unsigned u; float f;} c; c.u = ((unsigned)s) << 16;
    return c.f;
}
__device__ __forceinline__ float ulo(unsigned u){ union{unsigned i; float f;} c; c.i = u << 16; return c.f; }
__device__ __forceinline__ float uhi(unsigned u){ union{unsigned i; float f;} c; c.i = u & 0xffff0000u; return c.f; }

// ---------------- degree count ----------------
__global__ void k_count(const int* __restrict__ edst, int* __restrict__ cnt, int E){
    int e = blockIdx.x * blockDim.x + threadIdx.x;
    if (e < E) atomicAdd(&cnt[edst[e]], 1);
}

// ---------------- scan phase 1: per-1024-chunk sums ----------------
__global__ __launch_bounds__(256) void k_bsum(const int* __restrict__ cnt, int* __restrict__ bsum, int N){
    int b = blockIdx.x, t = threadIdx.x;
    int s = 0;
#pragma unroll
    for (int i = 0; i < 4; ++i){
        int idx = b * 1024 + i * 256 + t;
        if (idx < N) s += cnt[idx];
    }
    for (int off = 32; off; off >>= 1) s += __shfl_down(s, off);
    __shared__ int ws[4];
    if ((t & 63) == 0) ws[t >> 6] = s;
    __syncthreads();
    if (t == 0) bsum[b] = ws[0] + ws[1] + ws[2] + ws[3];
}

// ---------------- scan phase 2: single-block exclusive scan of chunk sums ----------------
__global__ __launch_bounds__(256) void k_bscan(const int* __restrict__ bsum, int* __restrict__ bpre,
                                               int* __restrict__ rowptr, int B, int N, int E){
    __shared__ int arr[256];
    int t = threadIdx.x;
    int v = (t < B) ? bsum[t] : 0;
    arr[t] = v;
    for (int off = 1; off < 256; off <<= 1){
        __syncthreads();
        int x = (t >= off) ? arr[t - off] : 0;
        __syncthreads();
        arr[t] += x;
    }
    __syncthreads();
    if (t < B) bpre[t] = arr[t] - v;
    if (t == 0) rowptr[N] = E;
}

// ---------------- scan phase 3: within-chunk scan + rowptr/dis write ----------------
__global__ __launch_bounds__(1024) void k_scan3(const int* __restrict__ cnt, const int* __restrict__ bpre,
                                                int* __restrict__ rowptr, float* __restrict__ dis, int N){
    __shared__ int arr[1024];
    int b = blockIdx.x, t = threadIdx.x;
    int idx = b * 1024 + t;
    int c = (idx < N) ? cnt[idx] : 0;
    arr[t] = c;
    for (int off = 1; off < 1024; off <<= 1){
        __syncthreads();
        int x = (t >= off) ? arr[t - off] : 0;
        __syncthreads();
        arr[t] += x;
    }
    __syncthreads();
    if (idx < N){
        rowptr[idx] = bpre[b] + arr[t] - c;
        dis[idx] = rsqrtf(1.0f + (float)c);
    }
}

// ---------------- CSR fill + per-entry coef ----------------
__global__ void k_fill(const int* __restrict__ esrc, const int* __restrict__ edst,
                       const int* __restrict__ rowptr, int* __restrict__ cursor,
                       const float* __restrict__ dis, int* __restrict__ csrc,
                       float* __restrict__ ccoef, int E){
    int e = blockIdx.x * blockDim.x + threadIdx.x;
    if (e < E){
        int s = esrc[e], d = edst[e];
        int pos = rowptr[d] + atomicAdd(&cursor[d], 1);
        csrc[pos] = s;
        ccoef[pos] = dis[s] * dis[d];
    }
}

__device__ __forceinline__ float f4c(float4 v, int j){
    return (j == 0) ? v.x : (j == 1) ? v.y : (j == 2) ? v.z : v.w;
}

// ---------------- fused inputBN + linear + BN + ReLU ----------------
__global__ __launch_bounds__(256) void k_lin(
    const float* __restrict__ x, const float* __restrict__ W,
    const float* __restrict__ bias, const float* __restrict__ ing, const float* __restrict__ inb,
    const float* __restrict__ g0, const float* __restrict__ b0,
    float* __restrict__ hout, int nrows)
{
    __shared__ __align__(16) float sA[64 * 68];
    __shared__ __align__(16) float sW[64 * 132];
    __shared__ float sing[128], sinb[128];
    int t = threadIdx.x;
    int row0 = blockIdx.x * 64;
    if (t < 128){ sing[t] = ing[t] * BN_S; sinb[t] = inb[t]; }
    int rg = t >> 5, cg = t & 31;
    float acc[8][4];
#pragma unroll
    for (int i = 0; i < 8; ++i)
#pragma unroll
        for (int j = 0; j < 4; ++j) acc[i][j] = 0.f;

    for (int c = 0; c < 2; ++c){
        __syncthreads();
        for (int i = t; i < 1024; i += 256){
            int r = i >> 4, k4 = (i & 15) * 4;
            int gr = row0 + r;
            float4 v = make_float4(0.f, 0.f, 0.f, 0.f);
            if (gr < nrows) v = *(const float4*)&x[(size_t)gr * HDIM + c * 64 + k4];
            int kb = c * 64 + k4;
            v.x = v.x * sing[kb + 0] + sinb[kb + 0];
            v.y = v.y * sing[kb + 1] + sinb[kb + 1];
            v.z = v.z * sing[kb + 2] + sinb[kb + 2];
            v.w = v.w * sing[kb + 3] + sinb[kb + 3];
            *(float4*)&sA[r * 68 + k4] = v;
        }
        for (int i = t; i < 2048; i += 256){
            int kk = i >> 5, n4 = (i & 31) * 4;
            *(float4*)&sW[kk * 132 + n4] = *(const float4*)&W[(size_t)(c * 64 + kk) * HDIM + n4];
        }
        __syncthreads();
        for (int kk = 0; kk < 64; kk += 4){
            float4 a[8];
#pragma unroll
            for (int i = 0; i < 8; ++i) a[i] = *(float4*)&sA[(rg * 8 + i) * 68 + kk];
#pragma unroll
            for (int j = 0; j < 4; ++j){
                float4 w = *(float4*)&sW[(kk + j) * 132 + cg * 4];
#pragma unroll
                for (int i = 0; i < 8; ++i){
                    float av = f4c(a[i], j);
                    acc[i][0] = fmaf(av, w.x, acc[i][0]);
                    acc[i][1] = fmaf(av, w.y, acc[i][1]);
                    acc[i][2] = fmaf(av, w.z, acc[i][2]);
                    acc[i][3] = fmaf(av, w.w, acc[i][3]);
                }
            }
        }
    }
    int col = cg * 4;
    float bs[4], gg[4], bb2[4];
#pragma unroll
    for (int j = 0; j < 4; ++j){ bs[j] = bias[col + j]; gg[j] = g0[col + j]; bb2[j] = b0[col + j]; }
#pragma unroll
    for (int i = 0; i < 8; ++i){
        int gr = row0 + rg * 8 + i;
        if (gr < nrows){
            float4 o;
            o.x = fmaxf(gg[0] * ((acc[i][0] + bs[0]) * BN_S) + bb2[0], 0.f);
            o.y = fmaxf(gg[1] * ((acc[i][1] + bs[1]) * BN_S) + bb2[1], 0.f);
            o.z = fmaxf(gg[2] * ((acc[i][2] + bs[2]) * BN_S) + bb2[2], 0.f);
            o.w = fmaxf(gg[3] * ((acc[i][3] + bs[3]) * BN_S) + bb2[3], 0.f);
            *(float4*)&hout[(size_t)gr * HDIM + col] = o;
        }
    }
}

// ---------------- hw = h @ W -> bf16-packed output ----------------
__global__ __launch_bounds__(256) void k_mm(
    const float* __restrict__ A, const float* __restrict__ W,
    unsigned* __restrict__ Cb, int nrows)
{
    __shared__ __align__(16) float sA[64 * 68];
    __shared__ __align__(16) float sW[64 * 132];
    int t = threadIdx.x;
    int row0 = blockIdx.x * 64;
    int rg = t >> 5, cg = t & 31;
    float acc[8][4];
#pragma unroll
    for (int i = 0; i < 8; ++i)
#pragma unroll
        for (int j = 0; j < 4; ++j) acc[i][j] = 0.f;

    for (int c = 0; c < 2; ++c){
        __syncthreads();
        for (int i = t; i < 1024; i += 256){
            int r = i >> 4, k4 = (i & 15) * 4;
            int gr = row0 + r;
            float4 v = make_float4(0.f, 0.f, 0.f, 0.f);
            if (gr < nrows) v = *(const float4*)&A[(size_t)gr * HDIM + c * 64 + k4];
            *(float4*)&sA[r * 68 + k4] = v;
        }
        for (int i = t; i < 2048; i += 256){
            int kk = i >> 5, n4 = (i & 31) * 4;
            *(float4*)&sW[kk * 132 + n4] = *(const float4*)&W[(size_t)(c * 64 + kk) * HDIM + n4];
        }
        __syncthreads();
        for (int kk = 0; kk < 64; kk += 4){
            float4 a[8];
#pragma unroll
            for (int i = 0; i < 8; ++i) a[i] = *(float4*)&sA[(rg * 8 + i) * 68 + kk];
#pragma unroll
            for (int j = 0; j < 4; ++j){
                float4 w = *(float4*)&sW[(kk + j) * 132 + cg * 4];
#pragma unroll
                for (int i = 0; i < 8; ++i){
                    float av = f4c(a[i], j);
                    acc[i][0] = fmaf(av, w.x, acc[i][0]);
                    acc[i][1] = fmaf(av, w.y, acc[i][1]);
                    acc[i][2] = fmaf(av, w.z, acc[i][2]);
                    acc[i][3] = fmaf(av, w.w, acc[i][3]);
                }
            }
        }
    }
#pragma unroll
    for (int i = 0; i < 8; ++i){
        int gr = row0 + rg * 8 + i;
        if (gr < nrows){
            uint2 o;
            o.x = (unsigned)f2bs(acc[i][0]) | ((unsigned)f2bs(acc[i][1]) << 16);
            o.y = (unsigned)f2bs(acc[i][2]) | ((unsigned)f2bs(acc[i][3]) << 16);
            *(uint2*)&Cb[(size_t)gr * 64 + cg * 2] = o;
        }
    }
}

// ---------------- CSR aggregate over bf16 hw, wave-per-row ----------------
__global__ __launch_bounds__(256) void k_agg(
    const unsigned* __restrict__ hwu, float* __restrict__ h,
    const int* __restrict__ rowptr, const int* __restrict__ csrc,
    const float* __restrict__ ccoef, const float* __restrict__ dis,
    const float* __restrict__ cb, const float* __restrict__ bg, const float* __restrict__ bb,
    int N)
{
    int row = blockIdx.x * 4 + (threadIdx.x >> 6);
    if (row >= N) return;
    int lane = threadIdx.x & 63;
    int b = rowptr[row], e = rowptr[row + 1];
    float ax = 0.f, ay = 0.f;
    int p = b;
    for (; p + 4 <= e; p += 4){
        int s0 = csrc[p], s1 = csrc[p + 1], s2 = csrc[p + 2], s3 = csrc[p + 3];
        float c0 = ccoef[p], c1 = ccoef[p + 1], c2 = ccoef[p + 2], c3 = ccoef[p + 3];
        unsigned v0 = hwu[(size_t)s0 * 64 + lane];
        unsigned v1 = hwu[(size_t)s1 * 64 + lane];
        unsigned v2 = hwu[(size_t)s2 * 64 + lane];
        unsigned v3 = hwu[(size_t)s3 * 64 + lane];
        ax = fmaf(ulo(v0), c0, ax); ay = fmaf(uhi(v0), c0, ay);
        ax = fmaf(ulo(v1), c1, ax); ay = fmaf(uhi(v1), c1, ay);
        ax = fmaf(ulo(v2), c2, ax); ay = fmaf(uhi(v2), c2, ay);
        ax = fmaf(ulo(v3), c3, ax); ay = fmaf(uhi(v3), c3, ay);
    }
    for (; p < e; ++p){
        int s = csrc[p];
        float c = ccoef[p];
        unsigned v = hwu[(size_t)s * 64 + lane];
        ax = fmaf(ulo(v), c, ax); ay = fmaf(uhi(v), c, ay);
    }
    float d = dis[row];
    float dd = d * d;
    unsigned us = hwu[(size_t)row * 64 + lane];
    float2 cbv = ((const float2*)cb)[lane];
    float2 gv  = ((const float2*)bg)[lane];
    float2 bv  = ((const float2*)bb)[lane];
    float vx = gv.x * ((ax + ulo(us) * dd + cbv.x) * BN_S) + bv.x;
    float vy = gv.y * ((ay + uhi(us) * dd + cbv.y) * BN_S) + bv.y;
    float2* h2 = (float2*)h;
    float2 cur = h2[(size_t)row * 64 + lane];
    cur.x += fmaxf(vx, 0.f);
    cur.y += fmaxf(vy, 0.f);
    h2[(size_t)row * 64 + lane] = cur;
}

// ---------------- gather xg = bf16(h[gidx]) ----------------
__global__ __launch_bounds__(256) void k_gather(const float* __restrict__ h, const int* __restrict__ gidx,
                                                unsigned* __restrict__ xg, int G){
    int id = blockIdx.x * blockDim.x + threadIdx.x;
    if (id >= G * 64) return;
    int row = id >> 6, kq = id & 63;
    int node = gidx[row];
    float2 v = ((const float2*)h)[(size_t)node * 64 + kq];
    xg[id] = (unsigned)f2bs(v.x) | ((unsigned)f2bs(v.y) << 16);
}

// ---------------- prepack head weights into B-fragment order ----------------
// pack1: [y(5)][nt(4)][kc(4)][lane(64)][j(8)] bf16 of W1[k=kc*32+(lane>>4)*8+j][n=nt*16+(lane&15)]
// pack2: [y(5)][nt(2)][kc(2)][lane(64)][j(8)] bf16 of W2[k][n], K=64, N=32
__global__ __launch_bounds__(256) void k_prep(
    const float* __restrict__ hW1, const float* __restrict__ oW1,
    const float* __restrict__ hW2, const float* __restrict__ oW2,
    unsigned short* __restrict__ p1, unsigned short* __restrict__ p2)
{
    int id = blockIdx.x * blockDim.x + threadIdx.x;
    if (id < 40960){
        int j = id & 7, lane = (id >> 3) & 63, kc = (id >> 9) & 3, nt = (id >> 11) & 3, y = id >> 13;
        int k = kc * 32 + (lane >> 4) * 8 + j;
        int n = nt * 16 + (lane & 15);
        float w = (y < 4) ? hW1[(y * 128 + k) * 64 + n] : oW1[k * 64 + n];
        p1[id] = f2bs(w);
    } else if (id < 51200){
        int id2 = id - 40960;
        int j = id2 & 7, lane = (id2 >> 3) & 63, kc = (id2 >> 9) & 1, nt = (id2 >> 10) & 1, y = id2 >> 11;
        int k = kc * 32 + (lane >> 4) * 8 + j;
        int n = nt * 16 + (lane & 15);
        float w = (y < 4) ? hW2[(y * 64 + k) * 32 + n] : oW2[k * 32 + n];
        p2[id2] = f2bs(w);
    }
}

// ---------------- MFMA fused heads: 64 games/block, 4 waves x 16 games ----------------
__global__ __launch_bounds__(256) void k_headmm(
    const unsigned* __restrict__ xg, const uint4* __restrict__ p1v, const uint4* __restrict__ p2v,
    const float* __restrict__ hb1, const float* __restrict__ hg1, const float* __restrict__ hbb1,
    const float* __restrict__ hb2,
    const float* __restrict__ hW3, const float* __restrict__ hb3,
    const float* __restrict__ ob1, const float* __restrict__ og1, const float* __restrict__ obb1,
    const float* __restrict__ ob2, const float* __restrict__ og2, const float* __restrict__ obb2,
    const float* __restrict__ oW3, const float* __restrict__ ob3,
    float* __restrict__ out, int G)
{
    __shared__ __align__(16) unsigned sxg[64 * 68];   // 64 games x 128 bf16 (k-pairs), pad 68
    __shared__ __align__(16) unsigned sz1u[64 * 36];  // 64 games x 64 bf16, pad 36
    __shared__ __align__(16) unsigned sz2u[64 * 20];  // 64 games x 32 bf16, pad 20
    __shared__ float sb1[64], sg1[64], sbb1[64];
    __shared__ float sb2[32], sg2[32], sbb2[32];
    __shared__ float sW3[96];
    __shared__ float sb3[3];

    int t = threadIdx.x;
    int gblk = blockIdx.x;   // game tile
    int y = blockIdx.y;      // head
    bool bn2 = (y == 4);
    int w = t >> 6, l = t & 63;
    int lanen = l & 15, quad = l >> 4;

    const float* b1  = bn2 ? ob1  : (hb1 + y * 64);
    const float* g1  = bn2 ? og1  : (hg1 + y * 64);
    const float* bb1 = bn2 ? obb1 : (hbb1 + y * 64);
    const float* b2  = bn2 ? ob2  : (hb2 + y * 32);
    const float* W3  = bn2 ? oW3  : (hW3 + y * 32);
    const float* b3  = bn2 ? ob3  : (hb3 + y);
    int nc3 = bn2 ? 3 : 1;

    // stage xg tile (64 rows x 64 uints)
    {
        int c4 = (t & 15) * 4;
        int rr = t >> 4;  // 0..15
#pragma unroll
        for (int i = 0; i < 4; ++i){
            int r = i * 16 + rr;
            int g = gblk * 64 + r;
            uint4 v = make_uint4(0, 0, 0, 0);
            if (g < G) v = *(const uint4*)&xg[(size_t)g * 64 + c4];
            *(uint4*)&sxg[r * 68 + c4] = v;
        }
    }
    if (t < 64){ sb1[t] = b1[t]; sg1[t] = g1[t]; sbb1[t] = bb1[t]; }
    else if (t < 96){
        int p = t - 64;
        sb2[p] = b2[p];
        sg2[p] = bn2 ? og2[p] : 1.f;
        sbb2[p] = bn2 ? obb2[p] : 0.f;
    }
    else if (t < 192){
        int i = t - 96;
        sW3[i] = (i < 32 * nc3) ? W3[i] : 0.f;
    }
    else if (t < 195){
        int i = t - 192;
        sb3[i] = (i < nc3) ? b3[i] : 0.f;
    }
    __syncthreads();

    // layer 1: [16 games x 128k] @ [128k x 64n] via MFMA, 4 n-tiles
    f32x4 acc1[4] = {{0.f,0.f,0.f,0.f},{0.f,0.f,0.f,0.f},{0.f,0.f,0.f,0.f},{0.f,0.f,0.f,0.f}};
#pragma unroll
    for (int kc = 0; kc < 4; ++kc){
        U128 a;
        a.u = *(const uint4*)&sxg[(w * 16 + lanen) * 68 + kc * 16 + quad * 4];
#pragma unroll
        for (int nt = 0; nt < 4; ++nt){
            U128 b;
            b.u = p1v[((y * 4 + nt) * 4 + kc) * 64 + l];
            acc1[nt] = __builtin_amdgcn_mfma_f32_16x16x32_bf16(a.s, b.s, acc1[nt], 0, 0, 0);
        }
    }
    // epilogue 1: BN + relu -> sz1 (bf16)
    {
        unsigned short* sz1s = (unsigned short*)sz1u;
#pragma unroll
        for (int nt = 0; nt < 4; ++nt){
            int n = nt * 16 + lanen;
            float g = sg1[n], bia = sb1[n], bt = sbb1[n];
#pragma unroll
            for (int r = 0; r < 4; ++r){
                int row = w * 16 + quad * 4 + r;
                float v = g * ((acc1[nt][r] + bia) * BN_S) + bt;
                sz1s[row * 72 + n] = f2bs(fmaxf(v, 0.f));
            }
        }
    }
    __syncthreads();

    // layer 2: [16 x 64k] @ [64k x 32n], 2 n-tiles
    f32x4 acc2[2] = {{0.f,0.f,0.f,0.f},{0.f,0.f,0.f,0.f}};
#pragma unroll
    for (int kc = 0; kc < 2; ++kc){
        U128 a;
        a.u = *(const uint4*)&sz1u[(w * 16 + lanen) * 36 + kc * 16 + quad * 4];
#pragma unroll
        for (int nt = 0; nt < 2; ++nt){
            U128 b;
            b.u = p2v[((y * 2 + nt) * 2 + kc) * 64 + l];
            acc2[nt] = __builtin_amdgcn_mfma_f32_16x16x32_bf16(a.s, b.s, acc2[nt], 0, 0, 0);
        }
    }
    // epilogue 2: (+BN for outcome) + relu -> sz2 (bf16)
    {
        unsigned short* sz2s = (unsigned short*)sz2u;
#pragma unroll
        for (int nt = 0; nt < 2; ++nt){
            int n = nt * 16 + lanen;
            float bia = sb2[n], g = sg2[n], bt = sbb2[n];
#pragma unroll
            for (int r = 0; r < 4; ++r){
                int row = w * 16 + quad * 4 + r;
                float v = acc2[nt][r] + bia;
                if (bn2) v = g * (v * BN_S) + bt;
                sz2s[row * 40 + n] = f2bs(fmaxf(v, 0.f));
            }
        }
    }
    __syncthreads();

    // layer 3
    const unsigned short* sz2s = (const unsigned short*)sz2u;
    if (!bn2){
        if (t < 64){
            int g = gblk * 64 + t;
            if (g < G){
                float s = sb3[0];
#pragma unroll
                for (int p = 0; p < 32; ++p) s = fmaf(bs2f(sz2s[t * 40 + p]), sW3[p], s);
                out[(size_t)g * 7 + y] = s;
            }
        }
    } else {
        if (t < 192){
            int gl = t / 3, c = t % 3;
            int g = gblk * 64 + gl;
            if (g < G){
                float s = sb3[c];
#pragma unroll
                for (int p = 0; p < 32; ++p) s = fmaf(bs2f(sz2s[gl * 40 + p]), sW3[p * 3 + c], s);
                out[(size_t)g * 7 + 4 + c] = s;
            }
        }
    }
}

extern "C" void kernel_launch(void* const* d_in, const int* in_sizes, int n_in,
                              void* d_out, int out_size, void* d_ws, size_t ws_size,
                              hipStream_t stream)
{
    const float* x    = (const float*)d_in[0];
    const int* esrc   = (const int*)d_in[1];
    const int* edst   = (const int*)d_in[2];
    const int* gidx   = (const int*)d_in[3];
    const float* in_g = (const float*)d_in[4];
    const float* in_b = (const float*)d_in[5];
    const float* lin_W = (const float*)d_in[6];
    const float* lin_b = (const float*)d_in[7];
    const float* bn0_g = (const float*)d_in[8];
    const float* bn0_b = (const float*)d_in[9];
    const float* cW[3] = {(const float*)d_in[10], (const float*)d_in[14], (const float*)d_in[18]};
    const float* cb[3] = {(const float*)d_in[11], (const float*)d_in[15], (const float*)d_in[19]};
    const float* bg[3] = {(const float*)d_in[12], (const float*)d_in[16], (const float*)d_in[20]};
    const float* bb[3] = {(const float*)d_in[13], (const float*)d_in[17], (const float*)d_in[21]};
    const float* hW1 = (const float*)d_in[22];
    const float* hb1 = (const float*)d_in[23];
    const float* hg1 = (const float*)d_in[24];
    const float* hbb1 = (const float*)d_in[25];
    const float* hW2 = (const float*)d_in[26];
    const float* hb2 = (const float*)d_in[27];
    const float* hW3 = (const float*)d_in[28];
    const float* hb3 = (const float*)d_in[29];
    const float* oW1 = (const float*)d_in[30];
    const float* ob1 = (const float*)d_in[31];
    const float* og1 = (const float*)d_in[32];
    const float* obb1 = (const float*)d_in[33];
    const float* oW2 = (const float*)d_in[34];
    const float* ob2 = (const float*)d_in[35];
    const float* og2 = (const float*)d_in[36];
    const float* obb2 = (const float*)d_in[37];
    const float* oW3 = (const float*)d_in[38];
    const float* ob3 = (const float*)d_in[39];

    const int N = in_sizes[0] / HDIM;
    const int E = in_sizes[1];
    const int G = in_sizes[3];

    char* wsp = (char*)d_ws;
    size_t off = 0;
    auto alloc = [&](size_t bytes) -> char* {
        char* p = wsp + off;
        off = (off + bytes + 255) & ~(size_t)255;
        return p;
    };
    float* dis    = (float*)alloc((size_t)N * 4);
    int* rowptr   = (int*)alloc((size_t)(N + 1) * 4);
    int* cnt      = (int*)alloc((size_t)N * 4);
    int* cursor   = (int*)alloc((size_t)N * 4);
    int* csrc     = (int*)alloc((size_t)E * 4);
    float* ccoef  = (float*)alloc((size_t)E * 4);
    float* hbuf   = (float*)alloc((size_t)N * HDIM * 4);
    unsigned* hwb = (unsigned*)alloc((size_t)N * 64 * 4);
    unsigned* xg  = (unsigned*)alloc((size_t)G * 64 * 4);
    unsigned short* p1 = (unsigned short*)alloc(40960 * 2);
    unsigned short* p2 = (unsigned short*)alloc(10240 * 2);
    int* bsum     = (int*)alloc(256 * 4);
    int* bpre     = (int*)alloc(256 * 4);

    hipMemsetAsync(cnt, 0, (size_t)N * 4, stream);
    hipMemsetAsync(cursor, 0, (size_t)N * 4, stream);

    int B = (N + 1023) / 1024;
    k_count<<<dim3((E + 255) / 256), dim3(256), 0, stream>>>(edst, cnt, E);
    k_bsum<<<dim3(B), dim3(256), 0, stream>>>(cnt, bsum, N);
    k_bscan<<<dim3(1), dim3(256), 0, stream>>>(bsum, bpre, rowptr, B, N, E);
    k_scan3<<<dim3(B), dim3(1024), 0, stream>>>(cnt, bpre, rowptr, dis, N);
    k_fill<<<dim3((E + 255) / 256), dim3(256), 0, stream>>>(esrc, edst, rowptr, cursor, dis, csrc, ccoef, E);
    k_prep<<<dim3(200), dim3(256), 0, stream>>>(hW1, oW1, hW2, oW2, p1, p2);

    int gb = (N + 63) / 64;
    k_lin<<<dim3(gb), dim3(256), 0, stream>>>(x, lin_W, lin_b, in_g, in_b, bn0_g, bn0_b, hbuf, N);
    for (int l = 0; l < 3; ++l){
        k_mm<<<dim3(gb), dim3(256), 0, stream>>>(hbuf, cW[l], hwb, N);
        k_agg<<<dim3((N + 3) / 4), dim3(256), 0, stream>>>(hwb, hbuf, rowptr, csrc, ccoef, dis,
                                                           cb[l], bg[l], bb[l], N);
    }
    k_gather<<<dim3((G * 64 + 255) / 256), dim3(256), 0, stream>>>(hbuf, gidx, xg, G);
    k_headmm<<<dim3((G + 63) / 64, 5), dim3(256), 0, stream>>>(
        xg, (const uint4*)p1, (const uint4*)p2,
        hb1, hg1, hbb1, hb2, hW3, hb3,
        ob1, og1, obb1, ob2, og2, obb2, oW3, ob3,
        (float*)d_out, G);
}

// Round 6
// 431.195 us; speedup vs baseline: 1.7355x; 1.1101x over previous
//
#include <hip/hip_runtime.h>
#include <hip/hip_bf16.h>

#define HDIM 128
static constexpr float BN_S = 0.99999500003749968751f; // 1/sqrt(1+1e-5)

typedef float f32x4 __attribute__((ext_vector_type(4)));
typedef short s16x8 __attribute__((ext_vector_type(8)));

union U128 { uint4 u; s16x8 s; };

__device__ __forceinline__ unsigned short f2bs(float f){
    union{float f; unsigned u;} c; c.f = f;
    unsigned r = c.u + 0x7fffu + ((c.u >> 16) & 1u);
    return (unsigned short)(r >> 16);
}
__device__ __forceinline__ float bs2f(unsigned short s){
    union{unsigned u; float f;} c; c.u = ((unsigned)s) << 16;
    return c.f;
}
__device__ __forceinline__ float ulo(unsigned u){ union{unsigned i; float f;} c; c.i = u << 16; return c.f; }
__device__ __forceinline__ float uhi(unsigned u){ union{unsigned i; float f;} c; c.i = u & 0xffff0000u; return c.f; }

// ---------------- degree count ----------------
__global__ void k_count(const int* __restrict__ edst, int* __restrict__ cnt, int E){
    int e = blockIdx.x * blockDim.x + threadIdx.x;
    if (e < E) atomicAdd(&cnt[edst[e]], 1);
}

// ---------------- scan phase 1: per-1024-chunk sums ----------------
__global__ __launch_bounds__(256) void k_bsum(const int* __restrict__ cnt, int* __restrict__ bsum, int N){
    int b = blockIdx.x, t = threadIdx.x;
    int s = 0;
#pragma unroll
    for (int i = 0; i < 4; ++i){
        int idx = b * 1024 + i * 256 + t;
        if (idx < N) s += cnt[idx];
    }
    for (int off = 32; off; off >>= 1) s += __shfl_down(s, off);
    __shared__ int ws[4];
    if ((t & 63) == 0) ws[t >> 6] = s;
    __syncthreads();
    if (t == 0) bsum[b] = ws[0] + ws[1] + ws[2] + ws[3];
}

// ---------------- scan phase 2: single-block exclusive scan of chunk sums ----------------
__global__ __launch_bounds__(256) void k_bscan(const int* __restrict__ bsum, int* __restrict__ bpre,
                                               int* __restrict__ rowptr, int B, int N, int E){
    __shared__ int arr[256];
    int t = threadIdx.x;
    int v = (t < B) ? bsum[t] : 0;
    arr[t] = v;
    for (int off = 1; off < 256; off <<= 1){
        __syncthreads();
        int x = (t >= off) ? arr[t - off] : 0;
        __syncthreads();
        arr[t] += x;
    }
    __syncthreads();
    if (t < B) bpre[t] = arr[t] - v;
    if (t == 0) rowptr[N] = E;
}

// ---------------- scan phase 3: within-chunk scan + rowptr/dis write ----------------
__global__ __launch_bounds__(1024) void k_scan3(const int* __restrict__ cnt, const int* __restrict__ bpre,
                                                int* __restrict__ rowptr, float* __restrict__ dis, int N){
    __shared__ int arr[1024];
    int b = blockIdx.x, t = threadIdx.x;
    int idx = b * 1024 + t;
    int c = (idx < N) ? cnt[idx] : 0;
    arr[t] = c;
    for (int off = 1; off < 1024; off <<= 1){
        __syncthreads();
        int x = (t >= off) ? arr[t - off] : 0;
        __syncthreads();
        arr[t] += x;
    }
    __syncthreads();
    if (idx < N){
        rowptr[idx] = bpre[b] + arr[t] - c;
        dis[idx] = rsqrtf(1.0f + (float)c);
    }
}

// ---------------- CSR fill: packed (src, coef) ----------------
__global__ void k_fill(const int* __restrict__ esrc, const int* __restrict__ edst,
                       const int* __restrict__ rowptr, int* __restrict__ cursor,
                       const float* __restrict__ dis, int2* __restrict__ ipk, int E){
    int e = blockIdx.x * blockDim.x + threadIdx.x;
    if (e < E){
        int s = esrc[e], d = edst[e];
        int pos = rowptr[d] + atomicAdd(&cursor[d], 1);
        ipk[pos] = make_int2(s, __float_as_int(dis[s] * dis[d]));
    }
}

// ---------------- prepack GEMM weights: split bf16 hi/lo in B-fragment order ----------------
// per mat: frag fi = ((nt*4 + kc)*2 + hilo)*64 + lane ; ushort addr = fi*8 + j
// element: k = kc*32 + (lane>>4)*8 + j ; n = nt*16 + (lane&15)
__global__ __launch_bounds__(256) void k_prepw(
    const float* __restrict__ linW, const float* __restrict__ cW1,
    const float* __restrict__ cW2, const float* __restrict__ cW3,
    unsigned short* __restrict__ wf)
{
    int id = blockIdx.x * 256 + threadIdx.x;   // 4 * 16384
    int mat = id >> 14;
    int el = id & 16383;
    int k = el >> 7, n = el & 127;
    const float* W = (mat == 0) ? linW : (mat == 1) ? cW1 : (mat == 2) ? cW2 : cW3;
    float v = W[k * 128 + n];
    unsigned short hs = f2bs(v);
    unsigned short ls = f2bs(v - bs2f(hs));
    int nt = n >> 4, lanen = n & 15, kc = k >> 5, quad = (k >> 3) & 3, j = k & 7;
    int lane = quad * 16 + lanen;
    size_t base = (size_t)mat * 32768;
    wf[base + (size_t)(((nt * 4 + kc) * 2 + 0) * 64 + lane) * 8 + j] = hs;
    wf[base + (size_t)(((nt * 4 + kc) * 2 + 1) * 64 + lane) * 8 + j] = ls;
}

// ---------------- unified MFMA GEMM (split-bf16, fp32-grade) ----------------
// mode 0: A=x with input-BN fold, epilogue BN+relu -> fp32 hout
// mode 1: A=h, epilogue raw -> bf16 hwout
__global__ __launch_bounds__(256, 4) void k_gemm(
    const float* __restrict__ A, const uint4* __restrict__ wf, int mode,
    const float* __restrict__ ing, const float* __restrict__ inb,
    const float* __restrict__ ebias, const float* __restrict__ eg, const float* __restrict__ eb,
    float* __restrict__ hout, unsigned short* __restrict__ hwout, int nrows)
{
    __shared__ __align__(16) unsigned sAhi[64 * 68];
    __shared__ __align__(16) unsigned sAlo[64 * 68];
    int t = threadIdx.x;
    int row0 = blockIdx.x * 64;
    bool ibn = (mode == 0);
    // stage + split A
    for (int i = t; i < 2048; i += 256){
        int r = i >> 5, q = i & 31;
        int gr = row0 + r;
        float4 v = make_float4(0.f, 0.f, 0.f, 0.f);
        if (gr < nrows) v = *(const float4*)&A[(size_t)gr * 128 + q * 4];
        if (ibn){
            float4 g = *(const float4*)&ing[q * 4];
            float4 bo = *(const float4*)&inb[q * 4];
            v.x = v.x * (g.x * BN_S) + bo.x;
            v.y = v.y * (g.y * BN_S) + bo.y;
            v.z = v.z * (g.z * BN_S) + bo.z;
            v.w = v.w * (g.w * BN_S) + bo.w;
        }
        unsigned short h0 = f2bs(v.x), h1 = f2bs(v.y), h2 = f2bs(v.z), h3 = f2bs(v.w);
        uint2 hi = make_uint2((unsigned)h0 | ((unsigned)h1 << 16), (unsigned)h2 | ((unsigned)h3 << 16));
        unsigned short l0 = f2bs(v.x - bs2f(h0)), l1 = f2bs(v.y - bs2f(h1));
        unsigned short l2 = f2bs(v.z - bs2f(h2)), l3 = f2bs(v.w - bs2f(h3));
        uint2 lo = make_uint2((unsigned)l0 | ((unsigned)l1 << 16), (unsigned)l2 | ((unsigned)l3 << 16));
        *(uint2*)&sAhi[r * 68 + q * 2] = hi;
        *(uint2*)&sAlo[r * 68 + q * 2] = lo;
    }
    __syncthreads();

    int w = t >> 6, l = t & 63;
    int lanen = l & 15, quad = l >> 4;
    int mrow = w * 16 + lanen;
    f32x4 acc[8];
#pragma unroll
    for (int i = 0; i < 8; ++i) acc[i] = (f32x4){0.f, 0.f, 0.f, 0.f};

#pragma unroll
    for (int kc = 0; kc < 4; ++kc){
        U128 ahi, alo;
        ahi.u = *(const uint4*)&sAhi[mrow * 68 + kc * 16 + quad * 4];
        alo.u = *(const uint4*)&sAlo[mrow * 68 + kc * 16 + quad * 4];
#pragma unroll
        for (int nt = 0; nt < 8; ++nt){
            U128 whi, wlo;
            whi.u = wf[((nt * 4 + kc) * 2 + 0) * 64 + l];
            wlo.u = wf[((nt * 4 + kc) * 2 + 1) * 64 + l];
            acc[nt] = __builtin_amdgcn_mfma_f32_16x16x32_bf16(ahi.s, whi.s, acc[nt], 0, 0, 0);
            acc[nt] = __builtin_amdgcn_mfma_f32_16x16x32_bf16(alo.s, whi.s, acc[nt], 0, 0, 0);
            acc[nt] = __builtin_amdgcn_mfma_f32_16x16x32_bf16(ahi.s, wlo.s, acc[nt], 0, 0, 0);
        }
    }
    // epilogue: C[row = w*16 + quad*4 + r][n = nt*16 + lanen]
    if (mode == 0){
#pragma unroll
        for (int nt = 0; nt < 8; ++nt){
            int n = nt * 16 + lanen;
            float bias = ebias[n], g = eg[n], bo = eb[n];
#pragma unroll
            for (int r = 0; r < 4; ++r){
                int grow = row0 + w * 16 + quad * 4 + r;
                if (grow < nrows){
                    float v = g * ((acc[nt][r] + bias) * BN_S) + bo;
                    hout[(size_t)grow * 128 + n] = fmaxf(v, 0.f);
                }
            }
        }
    } else {
#pragma unroll
        for (int nt = 0; nt < 8; ++nt){
            int n = nt * 16 + lanen;
#pragma unroll
            for (int r = 0; r < 4; ++r){
                int grow = row0 + w * 16 + quad * 4 + r;
                if (grow < nrows) hwout[(size_t)grow * 128 + n] = f2bs(acc[nt][r]);
            }
        }
    }
}

// ---------------- CSR aggregate: wave-per-row, 4 neighbors x 16 lanes x dwordx4 ----------------
__global__ __launch_bounds__(256) void k_agg(
    const unsigned* __restrict__ hwu, float* __restrict__ h,
    const int* __restrict__ rowptr, const int2* __restrict__ ipk,
    const float* __restrict__ dis,
    const float* __restrict__ cb, const float* __restrict__ bg, const float* __restrict__ bb,
    int N)
{
    int row = blockIdx.x * 4 + (threadIdx.x >> 6);
    if (row >= N) return;
    int l = threadIdx.x & 63;
    int sub = l >> 4, cg = l & 15;
    int b = rowptr[row], e = rowptr[row + 1];
    float acc[8];
#pragma unroll
    for (int i = 0; i < 8; ++i) acc[i] = 0.f;
#pragma unroll 2
    for (int p = b; p < e; p += 4){
        int q = p + sub;
        int2 ic = (q < e) ? ipk[q] : make_int2(0, 0);
        float c = __int_as_float(ic.y);
        uint4 v = *(const uint4*)&hwu[(size_t)ic.x * 64 + cg * 4];
        acc[0] = fmaf(ulo(v.x), c, acc[0]); acc[1] = fmaf(uhi(v.x), c, acc[1]);
        acc[2] = fmaf(ulo(v.y), c, acc[2]); acc[3] = fmaf(uhi(v.y), c, acc[3]);
        acc[4] = fmaf(ulo(v.z), c, acc[4]); acc[5] = fmaf(uhi(v.z), c, acc[5]);
        acc[6] = fmaf(ulo(v.w), c, acc[6]); acc[7] = fmaf(uhi(v.w), c, acc[7]);
    }
#pragma unroll
    for (int i = 0; i < 8; ++i){
        acc[i] += __shfl_xor(acc[i], 16);
        acc[i] += __shfl_xor(acc[i], 32);
    }
    if (sub == 0){
        float d = dis[row];
        float dd = d * d;
        uint4 sv = *(const uint4*)&hwu[(size_t)row * 64 + cg * 4];
        float sf[8] = {ulo(sv.x), uhi(sv.x), ulo(sv.y), uhi(sv.y),
                       ulo(sv.z), uhi(sv.z), ulo(sv.w), uhi(sv.w)};
        float4 c0 = *(const float4*)&cb[cg * 8], c1 = *(const float4*)&cb[cg * 8 + 4];
        float4 g0 = *(const float4*)&bg[cg * 8], g1 = *(const float4*)&bg[cg * 8 + 4];
        float4 b0 = *(const float4*)&bb[cg * 8], b1 = *(const float4*)&bb[cg * 8 + 4];
        float cc[8] = {c0.x, c0.y, c0.z, c0.w, c1.x, c1.y, c1.z, c1.w};
        float gg[8] = {g0.x, g0.y, g0.z, g0.w, g1.x, g1.y, g1.z, g1.w};
        float bo[8] = {b0.x, b0.y, b0.z, b0.w, b1.x, b1.y, b1.z, b1.w};
        float4 cur0 = *(float4*)&h[(size_t)row * 128 + cg * 8];
        float4 cur1 = *(float4*)&h[(size_t)row * 128 + cg * 8 + 4];
        float o[8] = {cur0.x, cur0.y, cur0.z, cur0.w, cur1.x, cur1.y, cur1.z, cur1.w};
#pragma unroll
        for (int i = 0; i < 8; ++i){
            float v = gg[i] * ((acc[i] + sf[i] * dd + cc[i]) * BN_S) + bo[i];
            o[i] += fmaxf(v, 0.f);
        }
        *(float4*)&h[(size_t)row * 128 + cg * 8] = make_float4(o[0], o[1], o[2], o[3]);
        *(float4*)&h[(size_t)row * 128 + cg * 8 + 4] = make_float4(o[4], o[5], o[6], o[7]);
    }
}

// ---------------- gather xg = bf16(h[gidx]) ----------------
__global__ __launch_bounds__(256) void k_gather(const float* __restrict__ h, const int* __restrict__ gidx,
                                                unsigned* __restrict__ xg, int G){
    int id = blockIdx.x * blockDim.x + threadIdx.x;
    if (id >= G * 64) return;
    int row = id >> 6, kq = id & 63;
    int node = gidx[row];
    float2 v = ((const float2*)h)[(size_t)node * 64 + kq];
    xg[id] = (unsigned)f2bs(v.x) | ((unsigned)f2bs(v.y) << 16);
}

// ---------------- prepack head weights into B-fragment order ----------------
__global__ __launch_bounds__(256) void k_prep(
    const float* __restrict__ hW1, const float* __restrict__ oW1,
    const float* __restrict__ hW2, const float* __restrict__ oW2,
    unsigned short* __restrict__ p1, unsigned short* __restrict__ p2)
{
    int id = blockIdx.x * blockDim.x + threadIdx.x;
    if (id < 40960){
        int j = id & 7, lane = (id >> 3) & 63, kc = (id >> 9) & 3, nt = (id >> 11) & 3, y = id >> 13;
        int k = kc * 32 + (lane >> 4) * 8 + j;
        int n = nt * 16 + (lane & 15);
        float w = (y < 4) ? hW1[(y * 128 + k) * 64 + n] : oW1[k * 64 + n];
        p1[id] = f2bs(w);
    } else if (id < 51200){
        int id2 = id - 40960;
        int j = id2 & 7, lane = (id2 >> 3) & 63, kc = (id2 >> 9) & 1, nt = (id2 >> 10) & 1, y = id2 >> 11;
        int k = kc * 32 + (lane >> 4) * 8 + j;
        int n = nt * 16 + (lane & 15);
        float w = (y < 4) ? hW2[(y * 64 + k) * 32 + n] : oW2[k * 32 + n];
        p2[id2] = f2bs(w);
    }
}

// ---------------- MFMA fused heads: 64 games/block, 4 waves x 16 games ----------------
__global__ __launch_bounds__(256) void k_headmm(
    const unsigned* __restrict__ xg, const uint4* __restrict__ p1v, const uint4* __restrict__ p2v,
    const float* __restrict__ hb1, const float* __restrict__ hg1, const float* __restrict__ hbb1,
    const float* __restrict__ hb2,
    const float* __restrict__ hW3, const float* __restrict__ hb3,
    const float* __restrict__ ob1, const float* __restrict__ og1, const float* __restrict__ obb1,
    const float* __restrict__ ob2, const float* __restrict__ og2, const float* __restrict__ obb2,
    const float* __restrict__ oW3, const float* __restrict__ ob3,
    float* __restrict__ out, int G)
{
    __shared__ __align__(16) unsigned sxg[64 * 68];
    __shared__ __align__(16) unsigned sz1u[64 * 36];
    __shared__ __align__(16) unsigned sz2u[64 * 20];
    __shared__ float sb1[64], sg1[64], sbb1[64];
    __shared__ float sb2[32], sg2[32], sbb2[32];
    __shared__ float sW3[96];
    __shared__ float sb3[3];

    int t = threadIdx.x;
    int gblk = blockIdx.x;
    int y = blockIdx.y;
    bool bn2 = (y == 4);
    int w = t >> 6, l = t & 63;
    int lanen = l & 15, quad = l >> 4;

    const float* b1  = bn2 ? ob1  : (hb1 + y * 64);
    const float* g1  = bn2 ? og1  : (hg1 + y * 64);
    const float* bb1 = bn2 ? obb1 : (hbb1 + y * 64);
    const float* b2  = bn2 ? ob2  : (hb2 + y * 32);
    const float* W3  = bn2 ? oW3  : (hW3 + y * 32);
    const float* b3  = bn2 ? ob3  : (hb3 + y);
    int nc3 = bn2 ? 3 : 1;

    {
        int c4 = (t & 15) * 4;
        int rr = t >> 4;
#pragma unroll
        for (int i = 0; i < 4; ++i){
            int r = i * 16 + rr;
            int g = gblk * 64 + r;
            uint4 v = make_uint4(0, 0, 0, 0);
            if (g < G) v = *(const uint4*)&xg[(size_t)g * 64 + c4];
            *(uint4*)&sxg[r * 68 + c4] = v;
        }
    }
    if (t < 64){ sb1[t] = b1[t]; sg1[t] = g1[t]; sbb1[t] = bb1[t]; }
    else if (t < 96){
        int p = t - 64;
        sb2[p] = b2[p];
        sg2[p] = bn2 ? og2[p] : 1.f;
        sbb2[p] = bn2 ? obb2[p] : 0.f;
    }
    else if (t < 192){
        int i = t - 96;
        sW3[i] = (i < 32 * nc3) ? W3[i] : 0.f;
    }
    else if (t < 195){
        int i = t - 192;
        sb3[i] = (i < nc3) ? b3[i] : 0.f;
    }
    __syncthreads();

    f32x4 acc1[4] = {{0.f,0.f,0.f,0.f},{0.f,0.f,0.f,0.f},{0.f,0.f,0.f,0.f},{0.f,0.f,0.f,0.f}};
#pragma unroll
    for (int kc = 0; kc < 4; ++kc){
        U128 a;
        a.u = *(const uint4*)&sxg[(w * 16 + lanen) * 68 + kc * 16 + quad * 4];
#pragma unroll
        for (int nt = 0; nt < 4; ++nt){
            U128 b;
            b.u = p1v[((y * 4 + nt) * 4 + kc) * 64 + l];
            acc1[nt] = __builtin_amdgcn_mfma_f32_16x16x32_bf16(a.s, b.s, acc1[nt], 0, 0, 0);
        }
    }
    {
        unsigned short* sz1s = (unsigned short*)sz1u;
#pragma unroll
        for (int nt = 0; nt < 4; ++nt){
            int n = nt * 16 + lanen;
            float g = sg1[n], bia = sb1[n], bt = sbb1[n];
#pragma unroll
            for (int r = 0; r < 4; ++r){
                int row = w * 16 + quad * 4 + r;
                float v = g * ((acc1[nt][r] + bia) * BN_S) + bt;
                sz1s[row * 72 + n] = f2bs(fmaxf(v, 0.f));
            }
        }
    }
    __syncthreads();

    f32x4 acc2[2] = {{0.f,0.f,0.f,0.f},{0.f,0.f,0.f,0.f}};
#pragma unroll
    for (int kc = 0; kc < 2; ++kc){
        U128 a;
        a.u = *(const uint4*)&sz1u[(w * 16 + lanen) * 36 + kc * 16 + quad * 4];
#pragma unroll
        for (int nt = 0; nt < 2; ++nt){
            U128 b;
            b.u = p2v[((y * 2 + nt) * 2 + kc) * 64 + l];
            acc2[nt] = __builtin_amdgcn_mfma_f32_16x16x32_bf16(a.s, b.s, acc2[nt], 0, 0, 0);
        }
    }
    {
        unsigned short* sz2s = (unsigned short*)sz2u;
#pragma unroll
        for (int nt = 0; nt < 2; ++nt){
            int n = nt * 16 + lanen;
            float bia = sb2[n], g = sg2[n], bt = sbb2[n];
#pragma unroll
            for (int r = 0; r < 4; ++r){
                int row = w * 16 + quad * 4 + r;
                float v = acc2[nt][r] + bia;
                if (bn2) v = g * (v * BN_S) + bt;
                sz2s[row * 40 + n] = f2bs(fmaxf(v, 0.f));
            }
        }
    }
    __syncthreads();

    const unsigned short* sz2s = (const unsigned short*)sz2u;
    if (!bn2){
        if (t < 64){
            int g = gblk * 64 + t;
            if (g < G){
                float s = sb3[0];
#pragma unroll
                for (int p = 0; p < 32; ++p) s = fmaf(bs2f(sz2s[t * 40 + p]), sW3[p], s);
                out[(size_t)g * 7 + y] = s;
            }
        }
    } else {
        if (t < 192){
            int gl = t / 3, c = t % 3;
            int g = gblk * 64 + gl;
            if (g < G){
                float s = sb3[c];
#pragma unroll
                for (int p = 0; p < 32; ++p) s = fmaf(bs2f(sz2s[gl * 40 + p]), sW3[p * 3 + c], s);
                out[(size_t)g * 7 + 4 + c] = s;
            }
        }
    }
}

extern "C" void kernel_launch(void* const* d_in, const int* in_sizes, int n_in,
                              void* d_out, int out_size, void* d_ws, size_t ws_size,
                              hipStream_t stream)
{
    const float* x    = (const float*)d_in[0];
    const int* esrc   = (const int*)d_in[1];
    const int* edst   = (const int*)d_in[2];
    const int* gidx   = (const int*)d_in[3];
    const float* in_g = (const float*)d_in[4];
    const float* in_b = (const float*)d_in[5];
    const float* lin_W = (const float*)d_in[6];
    const float* lin_b = (const float*)d_in[7];
    const float* bn0_g = (const float*)d_in[8];
    const float* bn0_b = (const float*)d_in[9];
    const float* cW[3] = {(const float*)d_in[10], (const float*)d_in[14], (const float*)d_in[18]};
    const float* cb[3] = {(const float*)d_in[11], (const float*)d_in[15], (const float*)d_in[19]};
    const float* bg[3] = {(const float*)d_in[12], (const float*)d_in[16], (const float*)d_in[20]};
    const float* bb[3] = {(const float*)d_in[13], (const float*)d_in[17], (const float*)d_in[21]};
    const float* hW1 = (const float*)d_in[22];
    const float* hb1 = (const float*)d_in[23];
    const float* hg1 = (const float*)d_in[24];
    const float* hbb1 = (const float*)d_in[25];
    const float* hW2 = (const float*)d_in[26];
    const float* hb2 = (const float*)d_in[27];
    const float* hW3 = (const float*)d_in[28];
    const float* hb3 = (const float*)d_in[29];
    const float* oW1 = (const float*)d_in[30];
    const float* ob1 = (const float*)d_in[31];
    const float* og1 = (const float*)d_in[32];
    const float* obb1 = (const float*)d_in[33];
    const float* oW2 = (const float*)d_in[34];
    const float* ob2 = (const float*)d_in[35];
    const float* og2 = (const float*)d_in[36];
    const float* obb2 = (const float*)d_in[37];
    const float* oW3 = (const float*)d_in[38];
    const float* ob3 = (const float*)d_in[39];

    const int N = in_sizes[0] / HDIM;
    const int E = in_sizes[1];
    const int G = in_sizes[3];

    char* wsp = (char*)d_ws;
    size_t off = 0;
    auto alloc = [&](size_t bytes) -> char* {
        char* p = wsp + off;
        off = (off + bytes + 255) & ~(size_t)255;
        return p;
    };
    float* dis    = (float*)alloc((size_t)N * 4);
    int* rowptr   = (int*)alloc((size_t)(N + 1) * 4);
    int* cnt      = (int*)alloc((size_t)N * 4);
    int* cursor   = (int*)alloc((size_t)N * 4);
    int2* ipk     = (int2*)alloc((size_t)E * 8);
    float* hbuf   = (float*)alloc((size_t)N * HDIM * 4);
    unsigned short* hwb = (unsigned short*)alloc((size_t)N * HDIM * 2);
    unsigned* xg  = (unsigned*)alloc((size_t)G * 64 * 4);
    unsigned short* p1 = (unsigned short*)alloc(40960 * 2);
    unsigned short* p2 = (unsigned short*)alloc(10240 * 2);
    unsigned short* wf = (unsigned short*)alloc((size_t)4 * 32768 * 2);
    int* bsum     = (int*)alloc(256 * 4);
    int* bpre     = (int*)alloc(256 * 4);

    hipMemsetAsync(cnt, 0, (size_t)N * 4, stream);
    hipMemsetAsync(cursor, 0, (size_t)N * 4, stream);

    int B = (N + 1023) / 1024;
    k_count<<<dim3((E + 255) / 256), dim3(256), 0, stream>>>(edst, cnt, E);
    k_bsum<<<dim3(B), dim3(256), 0, stream>>>(cnt, bsum, N);
    k_bscan<<<dim3(1), dim3(256), 0, stream>>>(bsum, bpre, rowptr, B, N, E);
    k_scan3<<<dim3(B), dim3(1024), 0, stream>>>(cnt, bpre, rowptr, dis, N);
    k_fill<<<dim3((E + 255) / 256), dim3(256), 0, stream>>>(esrc, edst, rowptr, cursor, dis, ipk, E);
    k_prep<<<dim3(200), dim3(256), 0, stream>>>(hW1, oW1, hW2, oW2, p1, p2);
    k_prepw<<<dim3(256), dim3(256), 0, stream>>>(lin_W, cW[0], cW[1], cW[2], wf);

    int gb = (N + 63) / 64;
    k_gemm<<<dim3(gb), dim3(256), 0, stream>>>(x, (const uint4*)wf, 0, in_g, in_b,
                                               lin_b, bn0_g, bn0_b, hbuf, (unsigned short*)nullptr, N);
    for (int l = 0; l < 3; ++l){
        k_gemm<<<dim3(gb), dim3(256), 0, stream>>>(hbuf, (const uint4*)(wf + (size_t)(1 + l) * 32768), 1,
                                                   nullptr, nullptr, nullptr, nullptr, nullptr,
                                                   nullptr, hwb, N);
        k_agg<<<dim3((N + 3) / 4), dim3(256), 0, stream>>>((const unsigned*)hwb, hbuf, rowptr, ipk,
                                                           dis, cb[l], bg[l], bb[l], N);
    }
    k_gather<<<dim3((G * 64 + 255) / 256), dim3(256), 0, stream>>>(hbuf, gidx, xg, G);
    k_headmm<<<dim3((G + 63) / 64, 5), dim3(256), 0, stream>>>(
        xg, (const uint4*)p1, (const uint4*)p2,
        hb1, hg1, hbb1, hb2, hW3, hb3,
        ob1, og1, obb1, ob2, og2, obb2, oW3, ob3,
        (float*)d_out, G);
}

// Round 7
// 424.241 us; speedup vs baseline: 1.7639x; 1.0164x over previous
//
#include <hip/hip_runtime.h>
#include <hip/hip_bf16.h>

#define HDIM 128
static constexpr float BN_S = 0.99999500003749968751f; // 1/sqrt(1+1e-5)

typedef float f32x4 __attribute__((ext_vector_type(4)));
typedef short s16x8 __attribute__((ext_vector_type(8)));

union U128 { uint4 u; s16x8 s; };

__device__ __forceinline__ unsigned short f2bs(float f){
    union{float f; unsigned u;} c; c.f = f;
    unsigned r = c.u + 0x7fffu + ((c.u >> 16) & 1u);
    return (unsigned short)(r >> 16);
}
__device__ __forceinline__ float bs2f(unsigned short s){
    union{unsigned u; float f;} c; c.u = ((unsigned)s) << 16;
    return c.f;
}
__device__ __forceinline__ float ulo(unsigned u){ union{unsigned i; float f;} c; c.i = u << 16; return c.f; }
__device__ __forceinline__ float uhi(unsigned u){ union{unsigned i; float f;} c; c.i = u & 0xffff0000u; return c.f; }

// ---------------- degree count ----------------
__global__ void k_count(const int* __restrict__ edst, int* __restrict__ cnt, int E){
    int e = blockIdx.x * blockDim.x + threadIdx.x;
    if (e < E) atomicAdd(&cnt[edst[e]], 1);
}

// ---------------- scan phase 1: per-1024-chunk sums ----------------
__global__ __launch_bounds__(256) void k_bsum(const int* __restrict__ cnt, int* __restrict__ bsum, int N){
    int b = blockIdx.x, t = threadIdx.x;
    int s = 0;
#pragma unroll
    for (int i = 0; i < 4; ++i){
        int idx = b * 1024 + i * 256 + t;
        if (idx < N) s += cnt[idx];
    }
    for (int off = 32; off; off >>= 1) s += __shfl_down(s, off);
    __shared__ int ws[4];
    if ((t & 63) == 0) ws[t >> 6] = s;
    __syncthreads();
    if (t == 0) bsum[b] = ws[0] + ws[1] + ws[2] + ws[3];
}

// ---------------- scan phase 2: single-block exclusive scan of chunk sums ----------------
__global__ __launch_bounds__(256) void k_bscan(const int* __restrict__ bsum, int* __restrict__ bpre,
                                               int* __restrict__ rowptr, int B, int N, int E){
    __shared__ int arr[256];
    int t = threadIdx.x;
    int v = (t < B) ? bsum[t] : 0;
    arr[t] = v;
    for (int off = 1; off < 256; off <<= 1){
        __syncthreads();
        int x = (t >= off) ? arr[t - off] : 0;
        __syncthreads();
        arr[t] += x;
    }
    __syncthreads();
    if (t < B) bpre[t] = arr[t] - v;
    if (t == 0) rowptr[N] = E;
}

// ---------------- scan phase 3: within-chunk scan + rowptr/dis write ----------------
__global__ __launch_bounds__(1024) void k_scan3(const int* __restrict__ cnt, const int* __restrict__ bpre,
                                                int* __restrict__ rowptr, float* __restrict__ dis, int N){
    __shared__ int arr[1024];
    int b = blockIdx.x, t = threadIdx.x;
    int idx = b * 1024 + t;
    int c = (idx < N) ? cnt[idx] : 0;
    arr[t] = c;
    for (int off = 1; off < 1024; off <<= 1){
        __syncthreads();
        int x = (t >= off) ? arr[t - off] : 0;
        __syncthreads();
        arr[t] += x;
    }
    __syncthreads();
    if (idx < N){
        rowptr[idx] = bpre[b] + arr[t] - c;
        dis[idx] = rsqrtf(1.0f + (float)c);
    }
}

// ---------------- CSR fill: packed (src, coef) ----------------
__global__ void k_fill(const int* __restrict__ esrc, const int* __restrict__ edst,
                       const int* __restrict__ rowptr, int* __restrict__ cursor,
                       const float* __restrict__ dis, int2* __restrict__ ipk, int E){
    int e = blockIdx.x * blockDim.x + threadIdx.x;
    if (e < E){
        int s = esrc[e], d = edst[e];
        int pos = rowptr[d] + atomicAdd(&cursor[d], 1);
        ipk[pos] = make_int2(s, __float_as_int(dis[s] * dis[d]));
    }
}

// ---------------- unified weight prepack ----------------
// GEMM wf (4 mats x 32768 ushort, split hi/lo B-frag order) + head p1/p2 (bf16 B-frag)
__global__ __launch_bounds__(256) void k_prepall(
    const float* __restrict__ linW, const float* __restrict__ cW1,
    const float* __restrict__ cW2, const float* __restrict__ cW3,
    const float* __restrict__ hW1, const float* __restrict__ oW1,
    const float* __restrict__ hW2, const float* __restrict__ oW2,
    unsigned short* __restrict__ wf, unsigned short* __restrict__ p1,
    unsigned short* __restrict__ p2)
{
    int id = blockIdx.x * 256 + threadIdx.x;
    if (id < 65536){
        int mat = id >> 14;
        int el = id & 16383;
        int k = el >> 7, n = el & 127;
        const float* W = (mat == 0) ? linW : (mat == 1) ? cW1 : (mat == 2) ? cW2 : cW3;
        float v = W[k * 128 + n];
        unsigned short hs = f2bs(v);
        unsigned short ls = f2bs(v - bs2f(hs));
        int nt = n >> 4, lanen = n & 15, kc = k >> 5, quad = (k >> 3) & 3, j = k & 7;
        int lane = quad * 16 + lanen;
        size_t base = (size_t)mat * 32768;
        wf[base + (size_t)(((nt * 4 + kc) * 2 + 0) * 64 + lane) * 8 + j] = hs;
        wf[base + (size_t)(((nt * 4 + kc) * 2 + 1) * 64 + lane) * 8 + j] = ls;
    } else {
        int id1 = id - 65536;
        if (id1 < 40960){
            int j = id1 & 7, lane = (id1 >> 3) & 63, kc = (id1 >> 9) & 3, nt = (id1 >> 11) & 3, y = id1 >> 13;
            int k = kc * 32 + (lane >> 4) * 8 + j;
            int n = nt * 16 + (lane & 15);
            float w = (y < 4) ? hW1[(y * 128 + k) * 64 + n] : oW1[k * 64 + n];
            p1[id1] = f2bs(w);
        } else if (id1 < 51200){
            int id2 = id1 - 40960;
            int j = id2 & 7, lane = (id2 >> 3) & 63, kc = (id2 >> 9) & 1, nt = (id2 >> 10) & 1, y = id2 >> 11;
            int k = kc * 32 + (lane >> 4) * 8 + j;
            int n = nt * 16 + (lane & 15);
            float w = (y < 4) ? hW2[(y * 64 + k) * 32 + n] : oW2[k * 32 + n];
            p2[id2] = f2bs(w);
        }
    }
}

// ---------------- unified MFMA GEMM (split-bf16, fp32-grade), B staged in LDS ----------------
// mode 0: A=x with input-BN fold, epilogue BN+relu -> fp32 hout
// mode 1: A=h, epilogue raw -> bf16 hwout
__global__ __launch_bounds__(256) void k_gemm(
    const float* __restrict__ A, const uint4* __restrict__ wf, int mode,
    const float* __restrict__ ing, const float* __restrict__ inb,
    const float* __restrict__ ebias, const float* __restrict__ eg, const float* __restrict__ eb,
    float* __restrict__ hout, unsigned short* __restrict__ hwout, int nrows)
{
    __shared__ __align__(16) unsigned sAhi[64 * 68];
    __shared__ __align__(16) unsigned sAlo[64 * 68];
    __shared__ __align__(16) uint4 sB[2048];   // one kc-half: nt(8) x kcl(2) x hilo(2) x lane(64)
    int t = threadIdx.x;
    int row0 = blockIdx.x * 64;
    bool ibn = (mode == 0);
    // stage + split A
    for (int i = t; i < 2048; i += 256){
        int r = i >> 5, q = i & 31;
        int gr = row0 + r;
        float4 v = make_float4(0.f, 0.f, 0.f, 0.f);
        if (gr < nrows) v = *(const float4*)&A[(size_t)gr * 128 + q * 4];
        if (ibn){
            float4 g = *(const float4*)&ing[q * 4];
            float4 bo = *(const float4*)&inb[q * 4];
            v.x = v.x * (g.x * BN_S) + bo.x;
            v.y = v.y * (g.y * BN_S) + bo.y;
            v.z = v.z * (g.z * BN_S) + bo.z;
            v.w = v.w * (g.w * BN_S) + bo.w;
        }
        unsigned short h0 = f2bs(v.x), h1 = f2bs(v.y), h2 = f2bs(v.z), h3 = f2bs(v.w);
        uint2 hi = make_uint2((unsigned)h0 | ((unsigned)h1 << 16), (unsigned)h2 | ((unsigned)h3 << 16));
        unsigned short l0 = f2bs(v.x - bs2f(h0)), l1 = f2bs(v.y - bs2f(h1));
        unsigned short l2 = f2bs(v.z - bs2f(h2)), l3 = f2bs(v.w - bs2f(h3));
        uint2 lo = make_uint2((unsigned)l0 | ((unsigned)l1 << 16), (unsigned)l2 | ((unsigned)l3 << 16));
        *(uint2*)&sAhi[r * 68 + q * 2] = hi;
        *(uint2*)&sAlo[r * 68 + q * 2] = lo;
    }
    // stage B half 0 (kc = 0,1)
    for (int i = t; i < 2048; i += 256){
        int lane = i & 63, rest = i >> 6;
        int hilo = rest & 1, kcl = (rest >> 1) & 1, nt = rest >> 2;
        sB[i] = wf[((nt * 4 + kcl) * 2 + hilo) * 64 + lane];
    }
    __syncthreads();

    int w = t >> 6, l = t & 63;
    int lanen = l & 15, quad = l >> 4;
    int mrow = w * 16 + lanen;
    f32x4 acc[8];
#pragma unroll
    for (int i = 0; i < 8; ++i) acc[i] = (f32x4){0.f, 0.f, 0.f, 0.f};

#pragma unroll
    for (int half = 0; half < 2; ++half){
        if (half){
            __syncthreads();
            for (int i = t; i < 2048; i += 256){
                int lane = i & 63, rest = i >> 6;
                int hilo = rest & 1, kcl = (rest >> 1) & 1, nt = rest >> 2;
                sB[i] = wf[((nt * 4 + 2 + kcl) * 2 + hilo) * 64 + lane];
            }
            __syncthreads();
        }
#pragma unroll
        for (int kcl = 0; kcl < 2; ++kcl){
            int kc = half * 2 + kcl;
            U128 ahi, alo;
            ahi.u = *(const uint4*)&sAhi[mrow * 68 + kc * 16 + quad * 4];
            alo.u = *(const uint4*)&sAlo[mrow * 68 + kc * 16 + quad * 4];
#pragma unroll
            for (int nt = 0; nt < 8; ++nt){
                U128 whi, wlo;
                whi.u = sB[((nt * 2 + kcl) * 2 + 0) * 64 + l];
                wlo.u = sB[((nt * 2 + kcl) * 2 + 1) * 64 + l];
                acc[nt] = __builtin_amdgcn_mfma_f32_16x16x32_bf16(ahi.s, whi.s, acc[nt], 0, 0, 0);
                acc[nt] = __builtin_amdgcn_mfma_f32_16x16x32_bf16(alo.s, whi.s, acc[nt], 0, 0, 0);
                acc[nt] = __builtin_amdgcn_mfma_f32_16x16x32_bf16(ahi.s, wlo.s, acc[nt], 0, 0, 0);
            }
        }
    }
    // epilogue: C[row = w*16 + quad*4 + r][n = nt*16 + lanen]
    if (mode == 0){
#pragma unroll
        for (int nt = 0; nt < 8; ++nt){
            int n = nt * 16 + lanen;
            float bias = ebias[n], g = eg[n], bo = eb[n];
#pragma unroll
            for (int r = 0; r < 4; ++r){
                int grow = row0 + w * 16 + quad * 4 + r;
                if (grow < nrows){
                    float v = g * ((acc[nt][r] + bias) * BN_S) + bo;
                    hout[(size_t)grow * 128 + n] = fmaxf(v, 0.f);
                }
            }
        }
    } else {
#pragma unroll
        for (int nt = 0; nt < 8; ++nt){
            int n = nt * 16 + lanen;
#pragma unroll
            for (int r = 0; r < 4; ++r){
                int grow = row0 + w * 16 + quad * 4 + r;
                if (grow < nrows) hwout[(size_t)grow * 128 + n] = f2bs(acc[nt][r]);
            }
        }
    }
}

// ---------------- CSR aggregate: wave-per-row, 16 neighbors/iter (4 per sub, 4 loads in flight) ----------------
__global__ __launch_bounds__(256) void k_agg(
    const unsigned* __restrict__ hwu, float* __restrict__ h,
    const int* __restrict__ rowptr, const int2* __restrict__ ipk,
    const float* __restrict__ dis,
    const float* __restrict__ cb, const float* __restrict__ bg, const float* __restrict__ bb,
    int N)
{
    int row = blockIdx.x * 4 + (threadIdx.x >> 6);
    if (row >= N) return;
    int l = threadIdx.x & 63;
    int sub = l >> 4, cg = l & 15;
    int b = rowptr[row], e = rowptr[row + 1];
    float acc[8];
#pragma unroll
    for (int i = 0; i < 8; ++i) acc[i] = 0.f;
    for (int p = b; p < e; p += 16){
        int base = p + sub * 4;
        int2 i0 = (base + 0 < e) ? ipk[base + 0] : make_int2(0, 0);
        int2 i1 = (base + 1 < e) ? ipk[base + 1] : make_int2(0, 0);
        int2 i2 = (base + 2 < e) ? ipk[base + 2] : make_int2(0, 0);
        int2 i3 = (base + 3 < e) ? ipk[base + 3] : make_int2(0, 0);
        uint4 v0 = *(const uint4*)&hwu[(size_t)i0.x * 64 + cg * 4];
        uint4 v1 = *(const uint4*)&hwu[(size_t)i1.x * 64 + cg * 4];
        uint4 v2 = *(const uint4*)&hwu[(size_t)i2.x * 64 + cg * 4];
        uint4 v3 = *(const uint4*)&hwu[(size_t)i3.x * 64 + cg * 4];
        float c0 = __int_as_float(i0.y), c1 = __int_as_float(i1.y);
        float c2 = __int_as_float(i2.y), c3 = __int_as_float(i3.y);
        acc[0] = fmaf(ulo(v0.x), c0, acc[0]); acc[1] = fmaf(uhi(v0.x), c0, acc[1]);
        acc[2] = fmaf(ulo(v0.y), c0, acc[2]); acc[3] = fmaf(uhi(v0.y), c0, acc[3]);
        acc[4] = fmaf(ulo(v0.z), c0, acc[4]); acc[5] = fmaf(uhi(v0.z), c0, acc[5]);
        acc[6] = fmaf(ulo(v0.w), c0, acc[6]); acc[7] = fmaf(uhi(v0.w), c0, acc[7]);
        acc[0] = fmaf(ulo(v1.x), c1, acc[0]); acc[1] = fmaf(uhi(v1.x), c1, acc[1]);
        acc[2] = fmaf(ulo(v1.y), c1, acc[2]); acc[3] = fmaf(uhi(v1.y), c1, acc[3]);
        acc[4] = fmaf(ulo(v1.z), c1, acc[4]); acc[5] = fmaf(uhi(v1.z), c1, acc[5]);
        acc[6] = fmaf(ulo(v1.w), c1, acc[6]); acc[7] = fmaf(uhi(v1.w), c1, acc[7]);
        acc[0] = fmaf(ulo(v2.x), c2, acc[0]); acc[1] = fmaf(uhi(v2.x), c2, acc[1]);
        acc[2] = fmaf(ulo(v2.y), c2, acc[2]); acc[3] = fmaf(uhi(v2.y), c2, acc[3]);
        acc[4] = fmaf(ulo(v2.z), c2, acc[4]); acc[5] = fmaf(uhi(v2.z), c2, acc[5]);
        acc[6] = fmaf(ulo(v2.w), c2, acc[6]); acc[7] = fmaf(uhi(v2.w), c2, acc[7]);
        acc[0] = fmaf(ulo(v3.x), c3, acc[0]); acc[1] = fmaf(uhi(v3.x), c3, acc[1]);
        acc[2] = fmaf(ulo(v3.y), c3, acc[2]); acc[3] = fmaf(uhi(v3.y), c3, acc[3]);
        acc[4] = fmaf(ulo(v3.z), c3, acc[4]); acc[5] = fmaf(uhi(v3.z), c3, acc[5]);
        acc[6] = fmaf(ulo(v3.w), c3, acc[6]); acc[7] = fmaf(uhi(v3.w), c3, acc[7]);
    }
#pragma unroll
    for (int i = 0; i < 8; ++i){
        acc[i] += __shfl_xor(acc[i], 16);
        acc[i] += __shfl_xor(acc[i], 32);
    }
    if (sub == 0){
        float d = dis[row];
        float dd = d * d;
        uint4 sv = *(const uint4*)&hwu[(size_t)row * 64 + cg * 4];
        float sf[8] = {ulo(sv.x), uhi(sv.x), ulo(sv.y), uhi(sv.y),
                       ulo(sv.z), uhi(sv.z), ulo(sv.w), uhi(sv.w)};
        float4 c0 = *(const float4*)&cb[cg * 8], c1 = *(const float4*)&cb[cg * 8 + 4];
        float4 g0 = *(const float4*)&bg[cg * 8], g1 = *(const float4*)&bg[cg * 8 + 4];
        float4 b0 = *(const float4*)&bb[cg * 8], b1 = *(const float4*)&bb[cg * 8 + 4];
        float cc[8] = {c0.x, c0.y, c0.z, c0.w, c1.x, c1.y, c1.z, c1.w};
        float gg[8] = {g0.x, g0.y, g0.z, g0.w, g1.x, g1.y, g1.z, g1.w};
        float bo[8] = {b0.x, b0.y, b0.z, b0.w, b1.x, b1.y, b1.z, b1.w};
        float4 cur0 = *(float4*)&h[(size_t)row * 128 + cg * 8];
        float4 cur1 = *(float4*)&h[(size_t)row * 128 + cg * 8 + 4];
        float o[8] = {cur0.x, cur0.y, cur0.z, cur0.w, cur1.x, cur1.y, cur1.z, cur1.w};
#pragma unroll
        for (int i = 0; i < 8; ++i){
            float v = gg[i] * ((acc[i] + sf[i] * dd + cc[i]) * BN_S) + bo[i];
            o[i] += fmaxf(v, 0.f);
        }
        *(float4*)&h[(size_t)row * 128 + cg * 8] = make_float4(o[0], o[1], o[2], o[3]);
        *(float4*)&h[(size_t)row * 128 + cg * 8 + 4] = make_float4(o[4], o[5], o[6], o[7]);
    }
}

// ---------------- MFMA fused heads (gather fused): 64 games/block, 4 waves x 16 games ----------------
__global__ __launch_bounds__(256) void k_headmm(
    const float* __restrict__ h, const int* __restrict__ gidx,
    const uint4* __restrict__ p1v, const uint4* __restrict__ p2v,
    const float* __restrict__ hb1, const float* __restrict__ hg1, const float* __restrict__ hbb1,
    const float* __restrict__ hb2,
    const float* __restrict__ hW3, const float* __restrict__ hb3,
    const float* __restrict__ ob1, const float* __restrict__ og1, const float* __restrict__ obb1,
    const float* __restrict__ ob2, const float* __restrict__ og2, const float* __restrict__ obb2,
    const float* __restrict__ oW3, const float* __restrict__ ob3,
    float* __restrict__ out, int G)
{
    __shared__ __align__(16) unsigned sxg[64 * 68];
    __shared__ __align__(16) unsigned sz1u[64 * 36];
    __shared__ __align__(16) unsigned sz2u[64 * 20];
    __shared__ float sb1[64], sg1[64], sbb1[64];
    __shared__ float sb2[32], sg2[32], sbb2[32];
    __shared__ float sW3[96];
    __shared__ float sb3[3];
    __shared__ int sgi[64];

    int t = threadIdx.x;
    int gblk = blockIdx.x;
    int y = blockIdx.y;
    bool bn2 = (y == 4);
    int w = t >> 6, l = t & 63;
    int lanen = l & 15, quad = l >> 4;

    const float* b1  = bn2 ? ob1  : (hb1 + y * 64);
    const float* g1  = bn2 ? og1  : (hg1 + y * 64);
    const float* bb1 = bn2 ? obb1 : (hbb1 + y * 64);
    const float* b2  = bn2 ? ob2  : (hb2 + y * 32);
    const float* W3  = bn2 ? oW3  : (hW3 + y * 32);
    const float* b3  = bn2 ? ob3  : (hb3 + y);
    int nc3 = bn2 ? 3 : 1;

    if (t < 64){
        sb1[t] = b1[t]; sg1[t] = g1[t]; sbb1[t] = bb1[t];
        if (t < 3) sb3[t] = (t < nc3) ? b3[t] : 0.f;
    } else if (t < 96){
        int p = t - 64;
        sb2[p] = b2[p];
        sg2[p] = bn2 ? og2[p] : 1.f;
        sbb2[p] = bn2 ? obb2[p] : 0.f;
    } else if (t < 192){
        int i = t - 96;
        sW3[i] = (i < 32 * nc3) ? W3[i] : 0.f;
    } else {
        int r = t - 192;
        int g = gblk * 64 + r;
        sgi[r] = (g < G) ? gidx[g] : 0;
    }
    __syncthreads();
    // gather + bf16-convert xg tile
    for (int i = t; i < 2048; i += 256){
        int r = i >> 5, c = i & 31;
        int node = sgi[r];
        float4 v = *(const float4*)&h[(size_t)node * 128 + c * 4];
        uint2 o = make_uint2((unsigned)f2bs(v.x) | ((unsigned)f2bs(v.y) << 16),
                             (unsigned)f2bs(v.z) | ((unsigned)f2bs(v.w) << 16));
        *(uint2*)&sxg[r * 68 + c * 2] = o;
    }
    __syncthreads();

    f32x4 acc1[4] = {{0.f,0.f,0.f,0.f},{0.f,0.f,0.f,0.f},{0.f,0.f,0.f,0.f},{0.f,0.f,0.f,0.f}};
#pragma unroll
    for (int kc = 0; kc < 4; ++kc){
        U128 a;
        a.u = *(const uint4*)&sxg[(w * 16 + lanen) * 68 + kc * 16 + quad * 4];
#pragma unroll
        for (int nt = 0; nt < 4; ++nt){
            U128 b;
            b.u = p1v[((y * 4 + nt) * 4 + kc) * 64 + l];
            acc1[nt] = __builtin_amdgcn_mfma_f32_16x16x32_bf16(a.s, b.s, acc1[nt], 0, 0, 0);
        }
    }
    {
        unsigned short* sz1s = (unsigned short*)sz1u;
#pragma unroll
        for (int nt = 0; nt < 4; ++nt){
            int n = nt * 16 + lanen;
            float g = sg1[n], bia = sb1[n], bt = sbb1[n];
#pragma unroll
            for (int r = 0; r < 4; ++r){
                int row = w * 16 + quad * 4 + r;
                float v = g * ((acc1[nt][r] + bia) * BN_S) + bt;
                sz1s[row * 72 + n] = f2bs(fmaxf(v, 0.f));
            }
        }
    }
    __syncthreads();

    f32x4 acc2[2] = {{0.f,0.f,0.f,0.f},{0.f,0.f,0.f,0.f}};
#pragma unroll
    for (int kc = 0; kc < 2; ++kc){
        U128 a;
        a.u = *(const uint4*)&sz1u[(w * 16 + lanen) * 36 + kc * 16 + quad * 4];
#pragma unroll
        for (int nt = 0; nt < 2; ++nt){
            U128 b;
            b.u = p2v[((y * 2 + nt) * 2 + kc) * 64 + l];
            acc2[nt] = __builtin_amdgcn_mfma_f32_16x16x32_bf16(a.s, b.s, acc2[nt], 0, 0, 0);
        }
    }
    {
        unsigned short* sz2s = (unsigned short*)sz2u;
#pragma unroll
        for (int nt = 0; nt < 2; ++nt){
            int n = nt * 16 + lanen;
            float bia = sb2[n], g = sg2[n], bt = sbb2[n];
#pragma unroll
            for (int r = 0; r < 4; ++r){
                int row = w * 16 + quad * 4 + r;
                float v = acc2[nt][r] + bia;
                if (bn2) v = g * (v * BN_S) + bt;
                sz2s[row * 40 + n] = f2bs(fmaxf(v, 0.f));
            }
        }
    }
    __syncthreads();

    const unsigned short* sz2s = (const unsigned short*)sz2u;
    if (!bn2){
        if (t < 64){
            int g = gblk * 64 + t;
            if (g < G){
                float s = sb3[0];
#pragma unroll
                for (int p = 0; p < 32; ++p) s = fmaf(bs2f(sz2s[t * 40 + p]), sW3[p], s);
                out[(size_t)g * 7 + y] = s;
            }
        }
    } else {
        if (t < 192){
            int gl = t / 3, c = t % 3;
            int g = gblk * 64 + gl;
            if (g < G){
                float s = sb3[c];
#pragma unroll
                for (int p = 0; p < 32; ++p) s = fmaf(bs2f(sz2s[gl * 40 + p]), sW3[p * 3 + c], s);
                out[(size_t)g * 7 + 4 + c] = s;
            }
        }
    }
}

extern "C" void kernel_launch(void* const* d_in, const int* in_sizes, int n_in,
                              void* d_out, int out_size, void* d_ws, size_t ws_size,
                              hipStream_t stream)
{
    const float* x    = (const float*)d_in[0];
    const int* esrc   = (const int*)d_in[1];
    const int* edst   = (const int*)d_in[2];
    const int* gidx   = (const int*)d_in[3];
    const float* in_g = (const float*)d_in[4];
    const float* in_b = (const float*)d_in[5];
    const float* lin_W = (const float*)d_in[6];
    const float* lin_b = (const float*)d_in[7];
    const float* bn0_g = (const float*)d_in[8];
    const float* bn0_b = (const float*)d_in[9];
    const float* cW[3] = {(const float*)d_in[10], (const float*)d_in[14], (const float*)d_in[18]};
    const float* cb[3] = {(const float*)d_in[11], (const float*)d_in[15], (const float*)d_in[19]};
    const float* bg[3] = {(const float*)d_in[12], (const float*)d_in[16], (const float*)d_in[20]};
    const float* bb[3] = {(const float*)d_in[13], (const float*)d_in[17], (const float*)d_in[21]};
    const float* hW1 = (const float*)d_in[22];
    const float* hb1 = (const float*)d_in[23];
    const float* hg1 = (const float*)d_in[24];
    const float* hbb1 = (const float*)d_in[25];
    const float* hW2 = (const float*)d_in[26];
    const float* hb2 = (const float*)d_in[27];
    const float* hW3 = (const float*)d_in[28];
    const float* hb3 = (const float*)d_in[29];
    const float* oW1 = (const float*)d_in[30];
    const float* ob1 = (const float*)d_in[31];
    const float* og1 = (const float*)d_in[32];
    const float* obb1 = (const float*)d_in[33];
    const float* oW2 = (const float*)d_in[34];
    const float* ob2 = (const float*)d_in[35];
    const float* og2 = (const float*)d_in[36];
    const float* obb2 = (const float*)d_in[37];
    const float* oW3 = (const float*)d_in[38];
    const float* ob3 = (const float*)d_in[39];

    const int N = in_sizes[0] / HDIM;
    const int E = in_sizes[1];
    const int G = in_sizes[3];

    char* wsp = (char*)d_ws;
    size_t off = 0;
    auto alloc = [&](size_t bytes) -> char* {
        char* p = wsp + off;
        off = (off + bytes + 255) & ~(size_t)255;
        return p;
    };
    float* dis    = (float*)alloc((size_t)N * 4);
    int* rowptr   = (int*)alloc((size_t)(N + 1) * 4);
    int* cntcur   = (int*)alloc((size_t)2 * N * 4);
    int* cnt      = cntcur;
    int* cursor   = cntcur + N;
    int2* ipk     = (int2*)alloc((size_t)E * 8);
    float* hbuf   = (float*)alloc((size_t)N * HDIM * 4);
    unsigned short* hwb = (unsigned short*)alloc((size_t)N * HDIM * 2);
    unsigned short* p1 = (unsigned short*)alloc(40960 * 2);
    unsigned short* p2 = (unsigned short*)alloc(10240 * 2);
    unsigned short* wf = (unsigned short*)alloc((size_t)4 * 32768 * 2);
    int* bsum     = (int*)alloc(256 * 4);
    int* bpre     = (int*)alloc(256 * 4);

    hipMemsetAsync(cntcur, 0, (size_t)2 * N * 4, stream);

    int B = (N + 1023) / 1024;
    k_count<<<dim3((E + 255) / 256), dim3(256), 0, stream>>>(edst, cnt, E);
    k_bsum<<<dim3(B), dim3(256), 0, stream>>>(cnt, bsum, N);
    k_bscan<<<dim3(1), dim3(256), 0, stream>>>(bsum, bpre, rowptr, B, N, E);
    k_scan3<<<dim3(B), dim3(1024), 0, stream>>>(cnt, bpre, rowptr, dis, N);
    k_fill<<<dim3((E + 255) / 256), dim3(256), 0, stream>>>(esrc, edst, rowptr, cursor, dis, ipk, E);
    k_prepall<<<dim3(456), dim3(256), 0, stream>>>(lin_W, cW[0], cW[1], cW[2],
                                                   hW1, oW1, hW2, oW2, wf, p1, p2);

    int gb = (N + 63) / 64;
    k_gemm<<<dim3(gb), dim3(256), 0, stream>>>(x, (const uint4*)wf, 0, in_g, in_b,
                                               lin_b, bn0_g, bn0_b, hbuf, (unsigned short*)nullptr, N);
    for (int l = 0; l < 3; ++l){
        k_gemm<<<dim3(gb), dim3(256), 0, stream>>>(hbuf, (const uint4*)(wf + (size_t)(1 + l) * 32768), 1,
                                                   nullptr, nullptr, nullptr, nullptr, nullptr,
                                                   nullptr, hwb, N);
        k_agg<<<dim3((N + 3) / 4), dim3(256), 0, stream>>>((const unsigned*)hwb, hbuf, rowptr, ipk,
                                                           dis, cb[l], bg[l], bb[l], N);
    }
    k_headmm<<<dim3((G + 63) / 64, 5), dim3(256), 0, stream>>>(
        hbuf, gidx, (const uint4*)p1, (const uint4*)p2,
        hb1, hg1, hbb1, hb2, hW3, hb3,
        ob1, og1, obb1, ob2, og2, obb2, oW3, ob3,
        (float*)d_out, G);
}

// Round 8
// 414.184 us; speedup vs baseline: 1.8068x; 1.0243x over previous
//
#include <hip/hip_runtime.h>
#include <hip/hip_bf16.h>

#define HDIM 128
static constexpr float BN_S = 0.99999500003749968751f; // 1/sqrt(1+1e-5)

typedef float f32x4 __attribute__((ext_vector_type(4)));
typedef short s16x8 __attribute__((ext_vector_type(8)));

union U128 { uint4 u; s16x8 s; };

__device__ __forceinline__ unsigned short f2bs(float f){
    union{float f; unsigned u;} c; c.f = f;
    unsigned r = c.u + 0x7fffu + ((c.u >> 16) & 1u);
    return (unsigned short)(r >> 16);
}
__device__ __forceinline__ float bs2f(unsigned short s){
    union{unsigned u; float f;} c; c.u = ((unsigned)s) << 16;
    return c.f;
}
__device__ __forceinline__ float ulo(unsigned u){ union{unsigned i; float f;} c; c.i = u << 16; return c.f; }
__device__ __forceinline__ float uhi(unsigned u){ union{unsigned i; float f;} c; c.i = u & 0xffff0000u; return c.f; }

// ---------------- degree count ----------------
__global__ void k_count(const int* __restrict__ edst, int* __restrict__ cnt, int E){
    int e = blockIdx.x * blockDim.x + threadIdx.x;
    if (e < E) atomicAdd(&cnt[edst[e]], 1);
}

// ---------------- scan phase 1: per-1024-chunk sums ----------------
__global__ __launch_bounds__(256) void k_bsum(const int* __restrict__ cnt, int* __restrict__ bsum, int N){
    int b = blockIdx.x, t = threadIdx.x;
    int s = 0;
#pragma unroll
    for (int i = 0; i < 4; ++i){
        int idx = b * 1024 + i * 256 + t;
        if (idx < N) s += cnt[idx];
    }
    for (int off = 32; off; off >>= 1) s += __shfl_down(s, off);
    __shared__ int ws[4];
    if ((t & 63) == 0) ws[t >> 6] = s;
    __syncthreads();
    if (t == 0) bsum[b] = ws[0] + ws[1] + ws[2] + ws[3];
}

// ---------------- scan phase 2: single-block exclusive scan of chunk sums ----------------
__global__ __launch_bounds__(256) void k_bscan(const int* __restrict__ bsum, int* __restrict__ bpre,
                                               int* __restrict__ rowptr, int B, int N, int E){
    __shared__ int arr[256];
    int t = threadIdx.x;
    int v = (t < B) ? bsum[t] : 0;
    arr[t] = v;
    for (int off = 1; off < 256; off <<= 1){
        __syncthreads();
        int x = (t >= off) ? arr[t - off] : 0;
        __syncthreads();
        arr[t] += x;
    }
    __syncthreads();
    if (t < B) bpre[t] = arr[t] - v;
    if (t == 0) rowptr[N] = E;
}

// ---------------- scan phase 3: within-chunk scan + rowptr/dis write ----------------
__global__ __launch_bounds__(1024) void k_scan3(const int* __restrict__ cnt, const int* __restrict__ bpre,
                                                int* __restrict__ rowptr, float* __restrict__ dis, int N){
    __shared__ int arr[1024];
    int b = blockIdx.x, t = threadIdx.x;
    int idx = b * 1024 + t;
    int c = (idx < N) ? cnt[idx] : 0;
    arr[t] = c;
    for (int off = 1; off < 1024; off <<= 1){
        __syncthreads();
        int x = (t >= off) ? arr[t - off] : 0;
        __syncthreads();
        arr[t] += x;
    }
    __syncthreads();
    if (idx < N){
        rowptr[idx] = bpre[b] + arr[t] - c;
        dis[idx] = rsqrtf(1.0f + (float)c);
    }
}

// ---------------- CSR fill: packed (src, coef) ----------------
__global__ void k_fill(const int* __restrict__ esrc, const int* __restrict__ edst,
                       const int* __restrict__ rowptr, int* __restrict__ cursor,
                       const float* __restrict__ dis, int2* __restrict__ ipk, int E){
    int e = blockIdx.x * blockDim.x + threadIdx.x;
    if (e < E){
        int s = esrc[e], d = edst[e];
        int pos = rowptr[d] + atomicAdd(&cursor[d], 1);
        ipk[pos] = make_int2(s, __float_as_int(dis[s] * dis[d]));
    }
}

// ---------------- unified weight prepack ----------------
__global__ __launch_bounds__(256) void k_prepall(
    const float* __restrict__ linW, const float* __restrict__ cW1,
    const float* __restrict__ cW2, const float* __restrict__ cW3,
    const float* __restrict__ hW1, const float* __restrict__ oW1,
    const float* __restrict__ hW2, const float* __restrict__ oW2,
    unsigned short* __restrict__ wf, unsigned short* __restrict__ p1,
    unsigned short* __restrict__ p2)
{
    int id = blockIdx.x * 256 + threadIdx.x;
    if (id < 65536){
        int mat = id >> 14;
        int el = id & 16383;
        int k = el >> 7, n = el & 127;
        const float* W = (mat == 0) ? linW : (mat == 1) ? cW1 : (mat == 2) ? cW2 : cW3;
        float v = W[k * 128 + n];
        unsigned short hs = f2bs(v);
        unsigned short ls = f2bs(v - bs2f(hs));
        int nt = n >> 4, lanen = n & 15, kc = k >> 5, quad = (k >> 3) & 3, j = k & 7;
        int lane = quad * 16 + lanen;
        size_t base = (size_t)mat * 32768;
        wf[base + (size_t)(((nt * 4 + kc) * 2 + 0) * 64 + lane) * 8 + j] = hs;
        wf[base + (size_t)(((nt * 4 + kc) * 2 + 1) * 64 + lane) * 8 + j] = ls;
    } else {
        int id1 = id - 65536;
        if (id1 < 40960){
            int j = id1 & 7, lane = (id1 >> 3) & 63, kc = (id1 >> 9) & 3, nt = (id1 >> 11) & 3, y = id1 >> 13;
            int k = kc * 32 + (lane >> 4) * 8 + j;
            int n = nt * 16 + (lane & 15);
            float w = (y < 4) ? hW1[(y * 128 + k) * 64 + n] : oW1[k * 64 + n];
            p1[id1] = f2bs(w);
        } else if (id1 < 51200){
            int id2 = id1 - 40960;
            int j = id2 & 7, lane = (id2 >> 3) & 63, kc = (id2 >> 9) & 1, nt = (id2 >> 10) & 1, y = id2 >> 11;
            int k = kc * 32 + (lane >> 4) * 8 + j;
            int n = nt * 16 + (lane & 15);
            float w = (y < 4) ? hW2[(y * 64 + k) * 32 + n] : oW2[k * 32 + n];
            p2[id2] = f2bs(w);
        }
    }
}

// ---------------- unified MFMA GEMM (split-bf16, fp32-grade), B in registers ----------------
// mode 0: A=x with input-BN fold, epilogue BN+relu -> fp32 hout
// mode 1: A=h, epilogue raw -> bf16 hwout
__global__ __launch_bounds__(256) void k_gemm(
    const float* __restrict__ A, const uint4* __restrict__ wf, int mode,
    const float* __restrict__ ing, const float* __restrict__ inb,
    const float* __restrict__ ebias, const float* __restrict__ eg, const float* __restrict__ eb,
    float* __restrict__ hout, unsigned short* __restrict__ hwout, int nrows)
{
    __shared__ __align__(16) unsigned sAhi[64 * 68];
    __shared__ __align__(16) unsigned sAlo[64 * 68];
    int t = threadIdx.x;
    int row0 = blockIdx.x * 64;
    bool ibn = (mode == 0);
    // stage + split A: hi = truncate-to-bf16 (exact residual), lo = round(v - hi)
    for (int i = t; i < 2048; i += 256){
        int r = i >> 5, q = i & 31;
        int gr = row0 + r;
        float4 v = make_float4(0.f, 0.f, 0.f, 0.f);
        if (gr < nrows) v = *(const float4*)&A[(size_t)gr * 128 + q * 4];
        if (ibn){
            float4 g = *(const float4*)&ing[q * 4];
            float4 bo = *(const float4*)&inb[q * 4];
            v.x = v.x * (g.x * BN_S) + bo.x;
            v.y = v.y * (g.y * BN_S) + bo.y;
            v.z = v.z * (g.z * BN_S) + bo.z;
            v.w = v.w * (g.w * BN_S) + bo.w;
        }
        unsigned u0 = __float_as_uint(v.x), u1 = __float_as_uint(v.y);
        unsigned u2 = __float_as_uint(v.z), u3 = __float_as_uint(v.w);
        uint2 hi = make_uint2((u0 >> 16) | (u1 & 0xffff0000u), (u2 >> 16) | (u3 & 0xffff0000u));
        unsigned short l0 = f2bs(v.x - __uint_as_float(u0 & 0xffff0000u));
        unsigned short l1 = f2bs(v.y - __uint_as_float(u1 & 0xffff0000u));
        unsigned short l2 = f2bs(v.z - __uint_as_float(u2 & 0xffff0000u));
        unsigned short l3 = f2bs(v.w - __uint_as_float(u3 & 0xffff0000u));
        uint2 lo = make_uint2((unsigned)l0 | ((unsigned)l1 << 16), (unsigned)l2 | ((unsigned)l3 << 16));
        *(uint2*)&sAhi[r * 68 + q * 2] = hi;
        *(uint2*)&sAlo[r * 68 + q * 2] = lo;
    }
    __syncthreads();

    int w = t >> 6, l = t & 63;
    int lanen = l & 15, quad = l >> 4;
    int mrow = w * 16 + lanen;
    // A fragments in registers (8 x uint4)
    U128 Ahi[4], Alo[4];
#pragma unroll
    for (int kc = 0; kc < 4; ++kc){
        Ahi[kc].u = *(const uint4*)&sAhi[mrow * 68 + kc * 16 + quad * 4];
        Alo[kc].u = *(const uint4*)&sAlo[mrow * 68 + kc * 16 + quad * 4];
    }
    f32x4 acc[8];
#pragma unroll
    for (int i = 0; i < 8; ++i) acc[i] = (f32x4){0.f, 0.f, 0.f, 0.f};

#pragma unroll
    for (int nt = 0; nt < 8; ++nt){
        U128 whi[4], wlo[4];
#pragma unroll
        for (int kc = 0; kc < 4; ++kc){
            whi[kc].u = wf[((nt * 4 + kc) * 2 + 0) * 64 + l];
            wlo[kc].u = wf[((nt * 4 + kc) * 2 + 1) * 64 + l];
        }
#pragma unroll
        for (int kc = 0; kc < 4; ++kc){
            acc[nt] = __builtin_amdgcn_mfma_f32_16x16x32_bf16(Ahi[kc].s, whi[kc].s, acc[nt], 0, 0, 0);
            acc[nt] = __builtin_amdgcn_mfma_f32_16x16x32_bf16(Alo[kc].s, whi[kc].s, acc[nt], 0, 0, 0);
            acc[nt] = __builtin_amdgcn_mfma_f32_16x16x32_bf16(Ahi[kc].s, wlo[kc].s, acc[nt], 0, 0, 0);
        }
    }
    // epilogue: C[row = w*16 + quad*4 + r][n = nt*16 + lanen]
    if (mode == 0){
#pragma unroll
        for (int nt = 0; nt < 8; ++nt){
            int n = nt * 16 + lanen;
            float bias = ebias[n], g = eg[n], bo = eb[n];
#pragma unroll
            for (int r = 0; r < 4; ++r){
                int grow = row0 + w * 16 + quad * 4 + r;
                if (grow < nrows){
                    float v = g * ((acc[nt][r] + bias) * BN_S) + bo;
                    hout[(size_t)grow * 128 + n] = fmaxf(v, 0.f);
                }
            }
        }
    } else {
#pragma unroll
        for (int nt = 0; nt < 8; ++nt){
            int n = nt * 16 + lanen;
#pragma unroll
            for (int r = 0; r < 4; ++r){
                int grow = row0 + w * 16 + quad * 4 + r;
                if (grow < nrows) hwout[(size_t)grow * 128 + n] = f2bs(acc[nt][r]);
            }
        }
    }
}

// ---------------- CSR aggregate: wave-per-row, 16/iter with subgroup skip ----------------
__global__ __launch_bounds__(256) void k_agg(
    const unsigned* __restrict__ hwu, float* __restrict__ h,
    const int* __restrict__ rowptr, const int2* __restrict__ ipk,
    const float* __restrict__ dis,
    const float* __restrict__ cb, const float* __restrict__ bg, const float* __restrict__ bb,
    int N)
{
    int row = blockIdx.x * 4 + (threadIdx.x >> 6);
    if (row >= N) return;
    int l = threadIdx.x & 63;
    int sub = l >> 4, cg = l & 15;
    int b = rowptr[row], e = rowptr[row + 1];
    float acc[8];
#pragma unroll
    for (int i = 0; i < 8; ++i) acc[i] = 0.f;
    for (int p = b; p < e; p += 16){
        int base = p + sub * 4;
        if (base < e){
            int2 i0 = ipk[base];
            int2 i1 = (base + 1 < e) ? ipk[base + 1] : make_int2(i0.x, 0);
            int2 i2 = (base + 2 < e) ? ipk[base + 2] : make_int2(i0.x, 0);
            int2 i3 = (base + 3 < e) ? ipk[base + 3] : make_int2(i0.x, 0);
            uint4 v0 = *(const uint4*)&hwu[(size_t)i0.x * 64 + cg * 4];
            uint4 v1 = *(const uint4*)&hwu[(size_t)i1.x * 64 + cg * 4];
            uint4 v2 = *(const uint4*)&hwu[(size_t)i2.x * 64 + cg * 4];
            uint4 v3 = *(const uint4*)&hwu[(size_t)i3.x * 64 + cg * 4];
            float c0 = __int_as_float(i0.y), c1 = __int_as_float(i1.y);
            float c2 = __int_as_float(i2.y), c3 = __int_as_float(i3.y);
            acc[0] = fmaf(ulo(v0.x), c0, acc[0]); acc[1] = fmaf(uhi(v0.x), c0, acc[1]);
            acc[2] = fmaf(ulo(v0.y), c0, acc[2]); acc[3] = fmaf(uhi(v0.y), c0, acc[3]);
            acc[4] = fmaf(ulo(v0.z), c0, acc[4]); acc[5] = fmaf(uhi(v0.z), c0, acc[5]);
            acc[6] = fmaf(ulo(v0.w), c0, acc[6]); acc[7] = fmaf(uhi(v0.w), c0, acc[7]);
            acc[0] = fmaf(ulo(v1.x), c1, acc[0]); acc[1] = fmaf(uhi(v1.x), c1, acc[1]);
            acc[2] = fmaf(ulo(v1.y), c1, acc[2]); acc[3] = fmaf(uhi(v1.y), c1, acc[3]);
            acc[4] = fmaf(ulo(v1.z), c1, acc[4]); acc[5] = fmaf(uhi(v1.z), c1, acc[5]);
            acc[6] = fmaf(ulo(v1.w), c1, acc[6]); acc[7] = fmaf(uhi(v1.w), c1, acc[7]);
            acc[0] = fmaf(ulo(v2.x), c2, acc[0]); acc[1] = fmaf(uhi(v2.x), c2, acc[1]);
            acc[2] = fmaf(ulo(v2.y), c2, acc[2]); acc[3] = fmaf(uhi(v2.y), c2, acc[3]);
            acc[4] = fmaf(ulo(v2.z), c2, acc[4]); acc[5] = fmaf(uhi(v2.z), c2, acc[5]);
            acc[6] = fmaf(ulo(v2.w), c2, acc[6]); acc[7] = fmaf(uhi(v2.w), c2, acc[7]);
            acc[0] = fmaf(ulo(v3.x), c3, acc[0]); acc[1] = fmaf(uhi(v3.x), c3, acc[1]);
            acc[2] = fmaf(ulo(v3.y), c3, acc[2]); acc[3] = fmaf(uhi(v3.y), c3, acc[3]);
            acc[4] = fmaf(ulo(v3.z), c3, acc[4]); acc[5] = fmaf(uhi(v3.z), c3, acc[5]);
            acc[6] = fmaf(ulo(v3.w), c3, acc[6]); acc[7] = fmaf(uhi(v3.w), c3, acc[7]);
        }
    }
#pragma unroll
    for (int i = 0; i < 8; ++i){
        acc[i] += __shfl_xor(acc[i], 16);
        acc[i] += __shfl_xor(acc[i], 32);
    }
    if (sub == 0){
        float d = dis[row];
        float dd = d * d;
        uint4 sv = *(const uint4*)&hwu[(size_t)row * 64 + cg * 4];
        float sf[8] = {ulo(sv.x), uhi(sv.x), ulo(sv.y), uhi(sv.y),
                       ulo(sv.z), uhi(sv.z), ulo(sv.w), uhi(sv.w)};
        float4 c0 = *(const float4*)&cb[cg * 8], c1 = *(const float4*)&cb[cg * 8 + 4];
        float4 g0 = *(const float4*)&bg[cg * 8], g1 = *(const float4*)&bg[cg * 8 + 4];
        float4 b0 = *(const float4*)&bb[cg * 8], b1 = *(const float4*)&bb[cg * 8 + 4];
        float cc[8] = {c0.x, c0.y, c0.z, c0.w, c1.x, c1.y, c1.z, c1.w};
        float gg[8] = {g0.x, g0.y, g0.z, g0.w, g1.x, g1.y, g1.z, g1.w};
        float bo[8] = {b0.x, b0.y, b0.z, b0.w, b1.x, b1.y, b1.z, b1.w};
        float4 cur0 = *(float4*)&h[(size_t)row * 128 + cg * 8];
        float4 cur1 = *(float4*)&h[(size_t)row * 128 + cg * 8 + 4];
        float o[8] = {cur0.x, cur0.y, cur0.z, cur0.w, cur1.x, cur1.y, cur1.z, cur1.w};
#pragma unroll
        for (int i = 0; i < 8; ++i){
            float v = gg[i] * ((acc[i] + sf[i] * dd + cc[i]) * BN_S) + bo[i];
            o[i] += fmaxf(v, 0.f);
        }
        *(float4*)&h[(size_t)row * 128 + cg * 8] = make_float4(o[0], o[1], o[2], o[3]);
        *(float4*)&h[(size_t)row * 128 + cg * 8 + 4] = make_float4(o[4], o[5], o[6], o[7]);
    }
}

// ---------------- MFMA fused heads (gather fused): 64 games/block, 4 waves x 16 games ----------------
__global__ __launch_bounds__(256) void k_headmm(
    const float* __restrict__ h, const int* __restrict__ gidx,
    const uint4* __restrict__ p1v, const uint4* __restrict__ p2v,
    const float* __restrict__ hb1, const float* __restrict__ hg1, const float* __restrict__ hbb1,
    const float* __restrict__ hb2,
    const float* __restrict__ hW3, const float* __restrict__ hb3,
    const float* __restrict__ ob1, const float* __restrict__ og1, const float* __restrict__ obb1,
    const float* __restrict__ ob2, const float* __restrict__ og2, const float* __restrict__ obb2,
    const float* __restrict__ oW3, const float* __restrict__ ob3,
    float* __restrict__ out, int G)
{
    __shared__ __align__(16) unsigned sxg[64 * 68];
    __shared__ __align__(16) unsigned sz1u[64 * 36];
    __shared__ __align__(16) unsigned sz2u[64 * 20];
    __shared__ float sb1[64], sg1[64], sbb1[64];
    __shared__ float sb2[32], sg2[32], sbb2[32];
    __shared__ float sW3[96];
    __shared__ float sb3[3];
    __shared__ int sgi[64];

    int t = threadIdx.x;
    int gblk = blockIdx.x;
    int y = blockIdx.y;
    bool bn2 = (y == 4);
    int w = t >> 6, l = t & 63;
    int lanen = l & 15, quad = l >> 4;

    const float* b1  = bn2 ? ob1  : (hb1 + y * 64);
    const float* g1  = bn2 ? og1  : (hg1 + y * 64);
    const float* bb1 = bn2 ? obb1 : (hbb1 + y * 64);
    const float* b2  = bn2 ? ob2  : (hb2 + y * 32);
    const float* W3  = bn2 ? oW3  : (hW3 + y * 32);
    const float* b3  = bn2 ? ob3  : (hb3 + y);
    int nc3 = bn2 ? 3 : 1;

    if (t < 64){
        sb1[t] = b1[t]; sg1[t] = g1[t]; sbb1[t] = bb1[t];
        if (t < 3) sb3[t] = (t < nc3) ? b3[t] : 0.f;
    } else if (t < 96){
        int p = t - 64;
        sb2[p] = b2[p];
        sg2[p] = bn2 ? og2[p] : 1.f;
        sbb2[p] = bn2 ? obb2[p] : 0.f;
    } else if (t < 192){
        int i = t - 96;
        sW3[i] = (i < 32 * nc3) ? W3[i] : 0.f;
    } else {
        int r = t - 192;
        int g = gblk * 64 + r;
        sgi[r] = (g < G) ? gidx[g] : 0;
    }
    __syncthreads();
    // gather + bf16-convert xg tile
    for (int i = t; i < 2048; i += 256){
        int r = i >> 5, c = i & 31;
        int node = sgi[r];
        float4 v = *(const float4*)&h[(size_t)node * 128 + c * 4];
        uint2 o = make_uint2((unsigned)f2bs(v.x) | ((unsigned)f2bs(v.y) << 16),
                             (unsigned)f2bs(v.z) | ((unsigned)f2bs(v.w) << 16));
        *(uint2*)&sxg[r * 68 + c * 2] = o;
    }
    __syncthreads();

    f32x4 acc1[4] = {{0.f,0.f,0.f,0.f},{0.f,0.f,0.f,0.f},{0.f,0.f,0.f,0.f},{0.f,0.f,0.f,0.f}};
#pragma unroll
    for (int kc = 0; kc < 4; ++kc){
        U128 a;
        a.u = *(const uint4*)&sxg[(w * 16 + lanen) * 68 + kc * 16 + quad * 4];
#pragma unroll
        for (int nt = 0; nt < 4; ++nt){
            U128 b;
            b.u = p1v[((y * 4 + nt) * 4 + kc) * 64 + l];
            acc1[nt] = __builtin_amdgcn_mfma_f32_16x16x32_bf16(a.s, b.s, acc1[nt], 0, 0, 0);
        }
    }
    {
        unsigned short* sz1s = (unsigned short*)sz1u;
#pragma unroll
        for (int nt = 0; nt < 4; ++nt){
            int n = nt * 16 + lanen;
            float g = sg1[n], bia = sb1[n], bt = sbb1[n];
#pragma unroll
            for (int r = 0; r < 4; ++r){
                int row = w * 16 + quad * 4 + r;
                float v = g * ((acc1[nt][r] + bia) * BN_S) + bt;
                sz1s[row * 72 + n] = f2bs(fmaxf(v, 0.f));
            }
        }
    }
    __syncthreads();

    f32x4 acc2[2] = {{0.f,0.f,0.f,0.f},{0.f,0.f,0.f,0.f}};
#pragma unroll
    for (int kc = 0; kc < 2; ++kc){
        U128 a;
        a.u = *(const uint4*)&sz1u[(w * 16 + lanen) * 36 + kc * 16 + quad * 4];
#pragma unroll
        for (int nt = 0; nt < 2; ++nt){
            U128 b;
            b.u = p2v[((y * 2 + nt) * 2 + kc) * 64 + l];
            acc2[nt] = __builtin_amdgcn_mfma_f32_16x16x32_bf16(a.s, b.s, acc2[nt], 0, 0, 0);
        }
    }
    {
        unsigned short* sz2s = (unsigned short*)sz2u;
#pragma unroll
        for (int nt = 0; nt < 2; ++nt){
            int n = nt * 16 + lanen;
            float bia = sb2[n], g = sg2[n], bt = sbb2[n];
#pragma unroll
            for (int r = 0; r < 4; ++r){
                int row = w * 16 + quad * 4 + r;
                float v = acc2[nt][r] + bia;
                if (bn2) v = g * (v * BN_S) + bt;
                sz2s[row * 40 + n] = f2bs(fmaxf(v, 0.f));
            }
        }
    }
    __syncthreads();

    const unsigned short* sz2s = (const unsigned short*)sz2u;
    if (!bn2){
        if (t < 64){
            int g = gblk * 64 + t;
            if (g < G){
                float s = sb3[0];
#pragma unroll
                for (int p = 0; p < 32; ++p) s = fmaf(bs2f(sz2s[t * 40 + p]), sW3[p], s);
                out[(size_t)g * 7 + y] = s;
            }
        }
    } else {
        if (t < 192){
            int gl = t / 3, c = t % 3;
            int g = gblk * 64 + gl;
            if (g < G){
                float s = sb3[c];
#pragma unroll
                for (int p = 0; p < 32; ++p) s = fmaf(bs2f(sz2s[gl * 40 + p]), sW3[p * 3 + c], s);
                out[(size_t)g * 7 + 4 + c] = s;
            }
        }
    }
}

extern "C" void kernel_launch(void* const* d_in, const int* in_sizes, int n_in,
                              void* d_out, int out_size, void* d_ws, size_t ws_size,
                              hipStream_t stream)
{
    const float* x    = (const float*)d_in[0];
    const int* esrc   = (const int*)d_in[1];
    const int* edst   = (const int*)d_in[2];
    const int* gidx   = (const int*)d_in[3];
    const float* in_g = (const float*)d_in[4];
    const float* in_b = (const float*)d_in[5];
    const float* lin_W = (const float*)d_in[6];
    const float* lin_b = (const float*)d_in[7];
    const float* bn0_g = (const float*)d_in[8];
    const float* bn0_b = (const float*)d_in[9];
    const float* cW[3] = {(const float*)d_in[10], (const float*)d_in[14], (const float*)d_in[18]};
    const float* cb[3] = {(const float*)d_in[11], (const float*)d_in[15], (const float*)d_in[19]};
    const float* bg[3] = {(const float*)d_in[12], (const float*)d_in[16], (const float*)d_in[20]};
    const float* bb[3] = {(const float*)d_in[13], (const float*)d_in[17], (const float*)d_in[21]};
    const float* hW1 = (const float*)d_in[22];
    const float* hb1 = (const float*)d_in[23];
    const float* hg1 = (const float*)d_in[24];
    const float* hbb1 = (const float*)d_in[25];
    const float* hW2 = (const float*)d_in[26];
    const float* hb2 = (const float*)d_in[27];
    const float* hW3 = (const float*)d_in[28];
    const float* hb3 = (const float*)d_in[29];
    const float* oW1 = (const float*)d_in[30];
    const float* ob1 = (const float*)d_in[31];
    const float* og1 = (const float*)d_in[32];
    const float* obb1 = (const float*)d_in[33];
    const float* oW2 = (const float*)d_in[34];
    const float* ob2 = (const float*)d_in[35];
    const float* og2 = (const float*)d_in[36];
    const float* obb2 = (const float*)d_in[37];
    const float* oW3 = (const float*)d_in[38];
    const float* ob3 = (const float*)d_in[39];

    const int N = in_sizes[0] / HDIM;
    const int E = in_sizes[1];
    const int G = in_sizes[3];

    char* wsp = (char*)d_ws;
    size_t off = 0;
    auto alloc = [&](size_t bytes) -> char* {
        char* p = wsp + off;
        off = (off + bytes + 255) & ~(size_t)255;
        return p;
    };
    float* dis    = (float*)alloc((size_t)N * 4);
    int* rowptr   = (int*)alloc((size_t)(N + 1) * 4);
    int* cntcur   = (int*)alloc((size_t)2 * N * 4);
    int* cnt      = cntcur;
    int* cursor   = cntcur + N;
    int2* ipk     = (int2*)alloc((size_t)E * 8);
    float* hbuf   = (float*)alloc((size_t)N * HDIM * 4);
    unsigned short* hwb = (unsigned short*)alloc((size_t)N * HDIM * 2);
    unsigned short* p1 = (unsigned short*)alloc(40960 * 2);
    unsigned short* p2 = (unsigned short*)alloc(10240 * 2);
    unsigned short* wf = (unsigned short*)alloc((size_t)4 * 32768 * 2);
    int* bsum     = (int*)alloc(256 * 4);
    int* bpre     = (int*)alloc(256 * 4);

    hipMemsetAsync(cntcur, 0, (size_t)2 * N * 4, stream);

    int B = (N + 1023) / 1024;
    k_count<<<dim3((E + 255) / 256), dim3(256), 0, stream>>>(edst, cnt, E);
    k_bsum<<<dim3(B), dim3(256), 0, stream>>>(cnt, bsum, N);
    k_bscan<<<dim3(1), dim3(256), 0, stream>>>(bsum, bpre, rowptr, B, N, E);
    k_scan3<<<dim3(B), dim3(1024), 0, stream>>>(cnt, bpre, rowptr, dis, N);
    k_fill<<<dim3((E + 255) / 256), dim3(256), 0, stream>>>(esrc, edst, rowptr, cursor, dis, ipk, E);
    k_prepall<<<dim3(456), dim3(256), 0, stream>>>(lin_W, cW[0], cW[1], cW[2],
                                                   hW1, oW1, hW2, oW2, wf, p1, p2);

    int gb = (N + 63) / 64;
    k_gemm<<<dim3(gb), dim3(256), 0, stream>>>(x, (const uint4*)wf, 0, in_g, in_b,
                                               lin_b, bn0_g, bn0_b, hbuf, (unsigned short*)nullptr, N);
    for (int l = 0; l < 3; ++l){
        k_gemm<<<dim3(gb), dim3(256), 0, stream>>>(hbuf, (const uint4*)(wf + (size_t)(1 + l) * 32768), 1,
                                                   nullptr, nullptr, nullptr, nullptr, nullptr,
                                                   nullptr, hwb, N);
        k_agg<<<dim3((N + 3) / 4), dim3(256), 0, stream>>>((const unsigned*)hwb, hbuf, rowptr, ipk,
                                                           dis, cb[l], bg[l], bb[l], N);
    }
    k_headmm<<<dim3((G + 63) / 64, 5), dim3(256), 0, stream>>>(
        hbuf, gidx, (const uint4*)p1, (const uint4*)p2,
        hb1, hg1, hbb1, hb2, hW3, hb3,
        ob1, og1, obb1, ob2, og2, obb2, oW3, ob3,
        (float*)d_out, G);
}